// Round 3
// baseline (5673.856 us; speedup 1.0000x reference)
//
#include <hip/hip_runtime.h>
#include <stdint.h>
#include <math.h>

#define NEG_INF (-__builtin_inff())
#define IDX_SENT 0x7fffffff

// ---------------------------------------------------------------------------
// JAX threefry2x32 (20 rounds), exact replication.
// ---------------------------------------------------------------------------
__device__ __forceinline__ void threefry2x32(uint32_t k0, uint32_t k1,
                                             uint32_t x0, uint32_t x1,
                                             uint32_t* o0, uint32_t* o1) {
  const uint32_t ks2 = k0 ^ k1 ^ 0x1BD11BDAu;
  uint32_t ks[3] = {k0, k1, ks2};
  const int rot[2][4] = {{13, 15, 26, 6}, {17, 29, 16, 24}};
  x0 += ks[0];
  x1 += ks[1];
#pragma unroll
  for (int i = 0; i < 5; ++i) {
#pragma unroll
    for (int j = 0; j < 4; ++j) {
      const int r = rot[i & 1][j];
      x0 += x1;
      x1 = (x1 << r) | (x1 >> (32 - r));
      x1 ^= x0;
    }
    x0 += ks[(i + 1) % 3];
    x1 += ks[(i + 2) % 3] + (uint32_t)(i + 1);
  }
  *o0 = x0;
  *o1 = x1;
}

__device__ __forceinline__ float bits_to_uniform(uint32_t bits) {
  return __uint_as_float((bits >> 9) | 0x3f800000u) - 1.0f;
}

// top3 ordered by (value desc, index asc) — matches jax.lax.top_k tie-break.
__device__ __forceinline__ void top3_insert(float v, int idx, float tv[3], int ti[3]) {
  if ((v > tv[2]) || (v == tv[2] && idx < ti[2])) {
    tv[2] = v; ti[2] = idx;
    if ((tv[2] > tv[1]) || (tv[2] == tv[1] && ti[2] < ti[1])) {
      float fv = tv[1]; int fi = ti[1];
      tv[1] = tv[2]; ti[1] = ti[2];
      tv[2] = fv;     ti[2] = fi;
      if ((tv[1] > tv[0]) || (tv[1] == tv[0] && ti[1] < ti[0])) {
        fv = tv[0]; fi = ti[0];
        tv[0] = tv[1]; ti[0] = ti[1];
        tv[1] = fv;    ti[1] = fi;
      }
    }
  }
}

// ---------------------------------------------------------------------------
// Weight transpose: w[oc][IC][3][3] -> wt[(ic*9+k)][64].
// ---------------------------------------------------------------------------
__global__ __launch_bounds__(256) void transpose_w4(
    const float* __restrict__ w, float* __restrict__ wt, int IC9) {
  const int idx = blockIdx.x * 256 + threadIdx.x;   // qrow*64 + oc
  const int qrow = idx >> 6;
  const int oc = idx & 63;
  const float4 v = *(const float4*)&w[(size_t)oc * IC9 + qrow * 4];
  wt[(size_t)(qrow * 4 + 0) * 64 + oc] = v.x;
  wt[(size_t)(qrow * 4 + 1) * 64 + oc] = v.y;
  wt[(size_t)(qrow * 4 + 2) * 64 + oc] = v.z;
  wt[(size_t)(qrow * 4 + 3) * 64 + oc] = v.w;
}

// ---------------------------------------------------------------------------
// conv3x3 (pad 1) + inference BN + ReLU.  x:[32,IC,64,64] wt:[(IC*9)][64]
// out:[32,64,64,64].
// Round-9: full-occupancy restructure. Rounds 7-8 showed idle fraction
// tracks waves/SIMD (2w: 37%, 4w: 29%) while VGPR=48 left 8-wave headroom
// unused — occupancy was capped by grid (2 blocks/CU), not resources.
// Grid: 32 b x 16 tiles x 2 oc-groups = 1024 blocks = 4 blocks/CU.
// Block: 512 threads = 8 waves; wave w in oc-group g owns ocs
// [g*32+4w, g*32+4w+4) -> 4 blocks/CU x 8 waves = 8 waves/SIMD (100% cap).
// Per-load intensity unchanged: one weight float4 -> 16 fma; per-wave
// SMEM stream halves (36 floats/ic — easy in-SGPR prefetch).
// oc-group is the TOP blockIdx bit: same-tile pairs are 512 apart = same
// XCD (512%8==0) -> L2 reuse of the duplicated x staging.
// Lane: r = lane&7 (row), lc = (lane>>3)*4 (4-col group). Row stride 36
// floats: ds_read_b128 at the 8-bank-cycle wave64 minimum (b64 tail is
// 2x-aliased — known ~8%, revisit if LDS pipe becomes the wall).
// Staging: wave w stages ic=w; lanes 0..33 cover the 34-col halo.
// Register prefetch of next icb + LDS double buffer, ONE barrier per icb.
// Accumulation order per output element: (icb, ic, ky, kx) — identical to
// all previous rounds => bit-identical numerics.
// ---------------------------------------------------------------------------
template <int IC>
__global__ __launch_bounds__(512, 8) void conv3x3_bn_relu(
    const float* __restrict__ x, const float* __restrict__ wt,
    const float* __restrict__ g, const float* __restrict__ bb,
    const float* __restrict__ m, const float* __restrict__ vv,
    float* __restrict__ out) {
  __shared__ float xs[2][8][10][36];   // dbuf x 8 ic x 10 halo rows x 36 cols (34 used)

  const int tid = threadIdx.x;
  const int blk = blockIdx.x;
  const int ocg = blk >> 9;          // oc-group 0..1 (top bit)
  const int b = (blk >> 4) & 31;
  const int tile = blk & 15;
  const int by = (tile >> 1) << 3;   // 8-row tile
  const int bx = (tile & 1) << 5;    // 32-col tile
  const int wv = __builtin_amdgcn_readfirstlane(tid >> 6);  // wave id 0..7
  const int lane = tid & 63;
  const int r = lane & 7;            // output row in tile
  const int lc = (lane >> 3) << 2;   // 0,4,..,28 col base (4 px)
  const int ocbase = (ocg << 5) + (wv << 2);  // wave-uniform oc base (4 ocs)

  // input staging decomposition: wave wv stages ic=wv, lanes 0..33 = cols
  const int sic = wv;
  const int sc = lane;               // halo col 0..33 active
  const int gx = bx + sc - 1;
  const bool cok = (sc < 34) && (gx >= 0) && (gx < 64);

  float acc[4][4];
#pragma unroll
  for (int p = 0; p < 4; ++p)
#pragma unroll
    for (int o = 0; o < 4; ++o) acc[p][o] = 0.0f;

  float pre[10];
  // ---- prologue: load + stage icb=0 into buffer 0 ----
  {
    const float* xp = x + ((size_t)b * IC + sic) * 4096;
#pragma unroll
    for (int rr = 0; rr < 10; ++rr) {
      const int gy = by + rr - 1;
      pre[rr] = 0.0f;
      if (cok && gy >= 0 && gy < 64) pre[rr] = xp[gy * 64 + gx];
    }
#pragma unroll
    for (int rr = 0; rr < 10; ++rr)
      if (sc < 34) xs[0][sic][rr][sc] = pre[rr];
  }
  __syncthreads();

  int cur = 0;
  for (int icb = 0; icb < IC; icb += 8) {
    const bool has_next = (icb + 8) < IC;
    // ---- issue next-icb global loads early (hidden under compute) ----
    if (has_next) {
      const float* xp = x + ((size_t)b * IC + icb + 8 + sic) * 4096;
#pragma unroll
      for (int rr = 0; rr < 10; ++rr) {
        const int gy = by + rr - 1;
        pre[rr] = 0.0f;
        if (cok && gy >= 0 && gy < 64) pre[rr] = xp[gy * 64 + gx];
      }
    }

    // ---- compute from current buffer ----
    const float* wbase = wt + (size_t)icb * 9 * 64 + ocbase;  // uniform
    for (int ic = 0; ic < 8; ++ic) {
#pragma unroll
      for (int ky = 0; ky < 3; ++ky) {
        float xv[6];
        *(float4*)&xv[0] = *(const float4*)&xs[cur][ic][r + ky][lc];
        *(float2*)&xv[4] = *(const float2*)&xs[cur][ic][r + ky][lc + 4];
#pragma unroll
        for (int kx = 0; kx < 3; ++kx) {
          // wave-uniform address -> s_load into SGPRs
          const float4 w4 = *(const float4*)(wbase + (ic * 9 + ky * 3 + kx) * 64);
#pragma unroll
          for (int p = 0; p < 4; ++p) {
            acc[p][0] = fmaf(xv[kx + p], w4.x, acc[p][0]);
            acc[p][1] = fmaf(xv[kx + p], w4.y, acc[p][1]);
            acc[p][2] = fmaf(xv[kx + p], w4.z, acc[p][2]);
            acc[p][3] = fmaf(xv[kx + p], w4.w, acc[p][3]);
          }
        }
      }
    }

    // ---- write prefetched tile into the other buffer, single barrier ----
    if (has_next) {
#pragma unroll
      for (int rr = 0; rr < 10; ++rr)
        if (sc < 34) xs[cur ^ 1][sic][rr][sc] = pre[rr];
    }
    __syncthreads();
    cur ^= 1;
  }

  // ---- epilogue: BN + ReLU + float4 store ----
#pragma unroll
  for (int o = 0; o < 4; ++o) {
    const int oc = ocbase + o;
    const float sc2 = g[oc] * (1.0f / sqrtf(vv[oc] + 1e-5f));
    const float sh = bb[oc] - m[oc] * sc2;
    float4 v;
    v.x = fmaxf(fmaf(acc[0][o], sc2, sh), 0.0f);
    v.y = fmaxf(fmaf(acc[1][o], sc2, sh), 0.0f);
    v.z = fmaxf(fmaf(acc[2][o], sc2, sh), 0.0f);
    v.w = fmaxf(fmaf(acc[3][o], sc2, sh), 0.0f);
    *(float4*)&out[(((size_t)b * 64 + oc) * 64 + (by + r)) * 64 + bx + lc] = v;
  }
}

// ---------------------------------------------------------------------------
// 1x1 conv (64->1) + bias into lg64[32][4096].  Grid 32*16 blocks.
// ---------------------------------------------------------------------------
__global__ __launch_bounds__(256) void logits64_k(
    const float* __restrict__ h2, const float* __restrict__ w3,
    const float* __restrict__ b3, float* __restrict__ lg64) {
  const int blk = blockIdx.x;
  const int b = blk >> 4;
  const int p = ((blk & 15) << 8) + threadIdx.x;
  __shared__ float wvv[64];
  if (threadIdx.x < 64) wvv[threadIdx.x] = w3[threadIdx.x];
  __syncthreads();
  float s = b3[0];
  const float* hp = h2 + (size_t)b * 64 * 4096 + p;
  for (int oc = 0; oc < 64; ++oc)
    s = fmaf(hp[(size_t)oc * 4096], wvv[oc], s);
  lg64[b * 4096 + p] = s;
}

// ---------------------------------------------------------------------------
// bilinear 64->256 (half-pixel, edge clamp) + sigmoid.
// ---------------------------------------------------------------------------
__global__ __launch_bounds__(256) void upsample_k(
    const float* __restrict__ lg64, float* __restrict__ logits,
    float* __restrict__ heat) {
  const int blk = blockIdx.x;
  const int b = blk >> 6;
  const int qq = ((blk & 63) << 10) + (threadIdx.x << 2);
  const float* lg = lg64 + b * 4096;
  const int oy = qq >> 8;
  const float sy = (float)oy * 0.25f - 0.375f;
  const float fy = floorf(sy);
  const int y0 = (int)fy;
  const float ty = sy - fy;
  const int y0c = y0 < 0 ? 0 : y0;
  const int y1c = (y0 + 1) > 63 ? 63 : (y0 + 1);
  const float* r0 = lg + y0c * 64;
  const float* r1 = lg + y1c * 64;
  float4 lo, he;
  float* lop = (float*)&lo;
  float* hep = (float*)&he;
#pragma unroll
  for (int j = 0; j < 4; ++j) {
    const int ox = (qq & 255) + j;
    const float sx = (float)ox * 0.25f - 0.375f;
    const float fx = floorf(sx);
    const int x0 = (int)fx;
    const float tx = sx - fx;
    const int x0c = x0 < 0 ? 0 : x0;
    const int x1c = (x0 + 1) > 63 ? 63 : (x0 + 1);
    const float v00 = r0[x0c], v01 = r0[x1c];
    const float v10 = r1[x0c], v11 = r1[x1c];
    const float vtop = v00 + (v01 - v00) * tx;
    const float vbot = v10 + (v11 - v10) * tx;
    const float val = vtop + (vbot - vtop) * ty;
    lop[j] = val;
    hep[j] = 1.0f / (1.0f + expf(-val));
  }
  const size_t o = (size_t)b * 65536 + qq;
  *(float4*)(logits + o) = lo;
  *(float4*)(heat + o) = he;
}

// ---------------------------------------------------------------------------
// Positive points, phase 1: per-stripe 9x9 NMS peak top3 + stripe argmax.
// ---------------------------------------------------------------------------
__global__ __launch_bounds__(256) void pos_stripe(
    const float* __restrict__ heat, float* __restrict__ cand) {
  const int b = blockIdx.x >> 4;
  const int stripe = blockIdx.x & 15;
  const int y0 = stripe << 4;
  const float* s = heat + (size_t)b * 65536;
  const int tid = threadIdx.x;
  __shared__ float sm[24][256];
  __shared__ float rm[24][256];
  __shared__ float rv[256 * 3];
  __shared__ int ri[256 * 3];
  __shared__ float mvv[256];
  __shared__ int mii[256];
  __shared__ float rv2[24];
  __shared__ int ri2[24];
  __shared__ float mv2[8];
  __shared__ int mi2[8];

  for (int l = tid; l < 24 * 256; l += 256) {
    const int rr = l >> 8, xx = l & 255;
    const int gy = y0 - 4 + rr;
    sm[rr][xx] = (gy >= 0 && gy < 256) ? s[gy * 256 + xx] : NEG_INF;
  }
  __syncthreads();
  for (int l = tid; l < 24 * 256; l += 256) {
    const int rr = l >> 8, xx = l & 255;
    const int lo = (xx - 4 < 0) ? 0 : xx - 4;
    const int hi = (xx + 4 > 255) ? 255 : xx + 4;
    float mx = NEG_INF;
    for (int x2 = lo; x2 <= hi; ++x2) mx = fmaxf(mx, sm[rr][x2]);
    rm[rr][xx] = mx;
  }
  __syncthreads();

  float tv[3] = {NEG_INF, NEG_INF, NEG_INF};
  int ti[3] = {IDX_SENT, IDX_SENT, IDX_SENT};
  float bmax = NEG_INF;
  int bidx = IDX_SENT;
  for (int l = tid; l < 16 * 256; l += 256) {
    const int ry = l >> 8, xx = l & 255;
    const int lr = ry + 4;
    const float v = sm[lr][xx];
    float lm = rm[lr - 4][xx];
#pragma unroll
    for (int d = -3; d <= 4; ++d) lm = fmaxf(lm, rm[lr + d][xx]);
    const int gidx = (y0 + ry) * 256 + xx;
    if (v > bmax) { bmax = v; bidx = gidx; }
    if (v == lm && v > 0.1f) top3_insert(v, gidx, tv, ti);
  }

  rv[tid * 3 + 0] = tv[0]; rv[tid * 3 + 1] = tv[1]; rv[tid * 3 + 2] = tv[2];
  ri[tid * 3 + 0] = ti[0]; ri[tid * 3 + 1] = ti[1]; ri[tid * 3 + 2] = ti[2];
  mvv[tid] = bmax; mii[tid] = bidx;
  __syncthreads();

  if (tid < 8) {
    float av[3] = {NEG_INF, NEG_INF, NEG_INF};
    int ai[3] = {IDX_SENT, IDX_SENT, IDX_SENT};
    float am = NEG_INF; int amI = IDX_SENT;
    for (int t = tid * 32; t < tid * 32 + 32; ++t) {
      for (int k = 0; k < 3; ++k) top3_insert(rv[t * 3 + k], ri[t * 3 + k], av, ai);
      if (mvv[t] > am || (mvv[t] == am && mii[t] < amI)) { am = mvv[t]; amI = mii[t]; }
    }
    rv2[tid * 3 + 0] = av[0]; rv2[tid * 3 + 1] = av[1]; rv2[tid * 3 + 2] = av[2];
    ri2[tid * 3 + 0] = ai[0]; ri2[tid * 3 + 1] = ai[1]; ri2[tid * 3 + 2] = ai[2];
    mv2[tid] = am; mi2[tid] = amI;
  }
  __syncthreads();

  if (tid == 0) {
    float fv[3] = {NEG_INF, NEG_INF, NEG_INF};
    int fi[3] = {IDX_SENT, IDX_SENT, IDX_SENT};
    for (int t = 0; t < 24; ++t) top3_insert(rv2[t], ri2[t], fv, fi);
    float gbv = NEG_INF; int gbi = IDX_SENT;
    for (int t = 0; t < 8; ++t)
      if (mv2[t] > gbv || (mv2[t] == gbv && mi2[t] < gbi)) { gbv = mv2[t]; gbi = mi2[t]; }
    float* c = cand + ((size_t)b * 16 + stripe) * 8;
    c[0] = fv[0]; c[1] = __int_as_float(fi[0]);
    c[2] = fv[1]; c[3] = __int_as_float(fi[1]);
    c[4] = fv[2]; c[5] = __int_as_float(fi[2]);
    c[6] = gbv;   c[7] = __int_as_float(gbi);
  }
}

// ---------------------------------------------------------------------------
// Positive points, phase 2: reduce 16 stripe candidates -> final outputs.
// ---------------------------------------------------------------------------
__global__ void pos_final(const float* __restrict__ cand,
                          float* __restrict__ coords, float* __restrict__ labels) {
  const int b = blockIdx.x;
  if (threadIdx.x != 0) return;
  float fv[3] = {NEG_INF, NEG_INF, NEG_INF};
  int fi[3] = {IDX_SENT, IDX_SENT, IDX_SENT};
  float gbv = NEG_INF; int gbi = IDX_SENT;
  for (int st = 0; st < 16; ++st) {
    const float* c = cand + ((size_t)b * 16 + st) * 8;
    for (int k = 0; k < 3; ++k)
      top3_insert(c[2 * k], __float_as_int(c[2 * k + 1]), fv, fi);
    const float mv = c[6]; const int mi = __float_as_int(c[7]);
    if (mv > gbv || (mv == gbv && mi < gbi)) { gbv = mv; gbi = mi; }
  }
  float* co = coords + (size_t)b * 10;
  float* la = labels + (size_t)b * 5;
  const bool any_peak = (fi[0] != IDX_SENT);
  const int i0 = any_peak ? fi[0] : gbi;
  co[0] = (float)(i0 & 255);
  co[1] = (float)(i0 >> 8);
  la[0] = 1.0f;
  for (int k = 1; k < 3; ++k) {
    const bool valid = (fi[k] != IDX_SENT);
    co[k * 2 + 0] = valid ? (float)(fi[k] & 255) : 0.0f;
    co[k * 2 + 1] = valid ? (float)(fi[k] >> 8) : 0.0f;
    la[k] = valid ? 1.0f : -1.0f;
  }
}

// ---------------------------------------------------------------------------
// Negative points, phase 1: per-64px-chunk count of (heat<0.3) + partial max.
// ---------------------------------------------------------------------------
__global__ __launch_bounds__(256) void neg_count(
    const float* __restrict__ heat, float* __restrict__ ncnt,
    float* __restrict__ pmax) {
  const int blk = blockIdx.x;
  const int b = blk >> 2;
  const int part = blk & 3;
  const int tid = threadIdx.x;
  const int chunk = (part << 8) + tid;
  const float4* s = (const float4*)(heat + (size_t)b * 65536 + chunk * 64);
  int c = 0;
  float mx = NEG_INF;
  for (int i = 0; i < 16; ++i) {
    const float4 v = s[i];
    c += (v.x < 0.3f) + (v.y < 0.3f) + (v.z < 0.3f) + (v.w < 0.3f);
    mx = fmaxf(mx, fmaxf(fmaxf(v.x, v.y), fmaxf(v.z, v.w)));
  }
  ncnt[b * 1024 + chunk] = (float)c;
  __shared__ float mxs[256];
  mxs[tid] = mx;
  __syncthreads();
  if (tid == 0) {
    float gmx = NEG_INF;
    for (int t = 0; t < 256; ++t) gmx = fmaxf(gmx, mxs[t]);
    pmax[blk] = gmx;
  }
}

// ---------------------------------------------------------------------------
// Negative points, phase 2: prefix, PRNG rank select, rescan.
// ---------------------------------------------------------------------------
__global__ __launch_bounds__(256) void neg_select(
    const float* __restrict__ heat, const float* __restrict__ ncnt,
    const float* __restrict__ pmax, float* __restrict__ coords,
    float* __restrict__ labels) {
  const int b = blockIdx.x;
  const int tid = threadIdx.x;
  const float* s = heat + (size_t)b * 65536;
  __shared__ float cnt[1024];
  __shared__ float c256[256];
  __shared__ int pfx[257];
  __shared__ float thr_s;
  __shared__ int fb_s;
  __shared__ int n_s;
  __shared__ int ridx_s[2];

  for (int l = tid; l < 1024; l += 256) cnt[l] = ncnt[b * 1024 + l];
  __syncthreads();
  c256[tid] = cnt[4 * tid] + cnt[4 * tid + 1] + cnt[4 * tid + 2] + cnt[4 * tid + 3];
  __syncthreads();
  if (tid == 0) {
    int tot = 0;
    for (int t = 0; t < 256; ++t) tot += (int)c256[t];
    const float gm = fmaxf(fmaxf(pmax[b * 4], pmax[b * 4 + 1]),
                           fmaxf(pmax[b * 4 + 2], pmax[b * 4 + 3]));
    fb_s = (tot > 0) ? 0 : 1;
    thr_s = (tot > 0) ? 0.3f : gm;
  }
  __syncthreads();
  if (fb_s) {
    const float t2 = thr_s;
    const int base = tid * 256;
    int c = 0;
    for (int i = 0; i < 256; ++i) c += (s[base + i] < t2) ? 1 : 0;
    c256[tid] = (float)c;
    __syncthreads();
  }
  if (tid == 0) {
    int run = 0;
    for (int t = 0; t < 256; ++t) { pfx[t] = run; run += (int)c256[t]; }
    pfx[256] = run;
    const int n = run;
    n_s = n;
    uint32_t k0, k1, a0, a1;
    threefry2x32(0u, 42u, 0u, (uint32_t)b, &k0, &k1);
    threefry2x32(k0, k1, 0u, 0u, &a0, &a1);
    const uint32_t bits0 = a0 ^ a1;
    threefry2x32(k0, k1, 0u, 1u, &a0, &a1);
    const uint32_t bits1 = a0 ^ a1;
    const float u0 = bits_to_uniform(bits0);
    const float u1 = bits_to_uniform(bits1);
    const float nf = (float)(n > 1 ? n : 1);
    int r0 = (int)(u0 * nf);
    int r1 = (int)(u1 * nf);
    const int rmax = (n - 1 > 0) ? n - 1 : 0;
    ridx_s[0] = r0 < rmax ? r0 : rmax;
    ridx_s[1] = r1 < rmax ? r1 : rmax;
    labels[(size_t)b * 5 + 3] = 0.0f;
    labels[(size_t)b * 5 + 4] = 0.0f;
    if (n == 0) {
      coords[(size_t)b * 10 + 6] = 0.0f; coords[(size_t)b * 10 + 7] = 0.0f;
      coords[(size_t)b * 10 + 8] = 0.0f; coords[(size_t)b * 10 + 9] = 0.0f;
    }
  }
  __syncthreads();
  const int n = n_s;
  if (n > 0) {
    const float t2 = thr_s;
    const int p0 = pfx[tid], p1 = pfx[tid + 1];
    const int base = tid * 256;
    for (int j = 0; j < 2; ++j) {
      const int r = ridx_s[j];
      if (r >= p0 && r < p1) {
        int need = r - p0;
        int sel = -1;
        for (int i = 0; i < 256; ++i) {
          if (s[base + i] < t2) {
            if (need == 0) { sel = base + i; break; }
            --need;
          }
        }
        coords[(size_t)b * 10 + 6 + j * 2 + 0] = (float)(sel & 255);
        coords[(size_t)b * 10 + 6 + j * 2 + 1] = (float)(sel >> 8);
      }
    }
  }
}

// ---------------------------------------------------------------------------
extern "C" void kernel_launch(void* const* d_in, const int* in_sizes, int n_in,
                              void* d_out, int out_size, void* d_ws, size_t ws_size,
                              hipStream_t stream) {
  (void)in_sizes; (void)n_in; (void)out_size; (void)ws_size;
  const float* x  = (const float*)d_in[0];
  const float* w1 = (const float*)d_in[1];
  const float* g1 = (const float*)d_in[2];
  const float* b1 = (const float*)d_in[3];
  const float* m1 = (const float*)d_in[4];
  const float* v1 = (const float*)d_in[5];
  const float* w2 = (const float*)d_in[6];
  const float* g2 = (const float*)d_in[7];
  const float* b2 = (const float*)d_in[8];
  const float* m2 = (const float*)d_in[9];
  const float* v2 = (const float*)d_in[10];
  const float* w3 = (const float*)d_in[11];
  const float* b3 = (const float*)d_in[12];

  float* out = (float*)d_out;
  float* heat = out;                         // [32,1,256,256]
  float* coords = out + (size_t)32 * 65536;  // [32,1,5,2]
  float* labels = coords + 320;              // [32,1,5]
  float* logits = labels + 160;              // [32,1,256,256]

  // Transposed weights live in the logits region (overwritten by upsample_k
  // only after both convs have consumed them — stream-ordered, no hazard).
  float* w1t = logits;            // 256*9*64 floats
  float* w2t = logits + 147456;   // 64*9*64 floats

  float* h1 = (float*)d_ws;                        // [32,64,64,64]
  float* h2 = h1 + (size_t)32 * 64 * 64 * 64;      // [32,64,64,64]
  float* lg64 = h1;                                // reuse after conv2
  float* cand = h1 + 131072;
  float* ncnt = h1 + 135168;
  float* pmax = h1 + 167936;

  transpose_w4<<<144, 256, 0, stream>>>(w1, w1t, 2304);
  transpose_w4<<<36, 256, 0, stream>>>(w2, w2t, 576);
  conv3x3_bn_relu<256><<<1024, 512, 0, stream>>>(x, w1t, g1, b1, m1, v1, h1);
  conv3x3_bn_relu<64><<<1024, 512, 0, stream>>>(h1, w2t, g2, b2, m2, v2, h2);
  logits64_k<<<512, 256, 0, stream>>>(h2, w3, b3, lg64);
  upsample_k<<<2048, 256, 0, stream>>>(lg64, logits, heat);
  pos_stripe<<<512, 256, 0, stream>>>(heat, cand);
  pos_final<<<32, 64, 0, stream>>>(cand, coords, labels);
  neg_count<<<128, 256, 0, stream>>>(heat, ncnt, pmax);
  neg_select<<<32, 256, 0, stream>>>(heat, ncnt, pmax, coords, labels);
}

// Round 4
// 3217.311 us; speedup vs baseline: 1.7635x; 1.7635x over previous
//
#include <hip/hip_runtime.h>
#include <stdint.h>
#include <math.h>

#define NEG_INF (-__builtin_inff())
#define IDX_SENT 0x7fffffff

// ---------------------------------------------------------------------------
// JAX threefry2x32 (20 rounds), exact replication.
// ---------------------------------------------------------------------------
__device__ __forceinline__ void threefry2x32(uint32_t k0, uint32_t k1,
                                             uint32_t x0, uint32_t x1,
                                             uint32_t* o0, uint32_t* o1) {
  const uint32_t ks2 = k0 ^ k1 ^ 0x1BD11BDAu;
  uint32_t ks[3] = {k0, k1, ks2};
  const int rot[2][4] = {{13, 15, 26, 6}, {17, 29, 16, 24}};
  x0 += ks[0];
  x1 += ks[1];
#pragma unroll
  for (int i = 0; i < 5; ++i) {
#pragma unroll
    for (int j = 0; j < 4; ++j) {
      const int r = rot[i & 1][j];
      x0 += x1;
      x1 = (x1 << r) | (x1 >> (32 - r));
      x1 ^= x0;
    }
    x0 += ks[(i + 1) % 3];
    x1 += ks[(i + 2) % 3] + (uint32_t)(i + 1);
  }
  *o0 = x0;
  *o1 = x1;
}

__device__ __forceinline__ float bits_to_uniform(uint32_t bits) {
  return __uint_as_float((bits >> 9) | 0x3f800000u) - 1.0f;
}

// top3 ordered by (value desc, index asc) — matches jax.lax.top_k tie-break.
__device__ __forceinline__ void top3_insert(float v, int idx, float tv[3], int ti[3]) {
  if ((v > tv[2]) || (v == tv[2] && idx < ti[2])) {
    tv[2] = v; ti[2] = idx;
    if ((tv[2] > tv[1]) || (tv[2] == tv[1] && ti[2] < ti[1])) {
      float fv = tv[1]; int fi = ti[1];
      tv[1] = tv[2]; ti[1] = ti[2];
      tv[2] = fv;     ti[2] = fi;
      if ((tv[1] > tv[0]) || (tv[1] == tv[0] && ti[1] < ti[0])) {
        fv = tv[0]; fi = ti[0];
        tv[0] = tv[1]; ti[0] = ti[1];
        tv[1] = fv;    ti[1] = fi;
      }
    }
  }
}

// ---------------------------------------------------------------------------
// Weight transpose: w[oc][IC][3][3] -> wt[(ic*9+k)][64].
// ---------------------------------------------------------------------------
__global__ __launch_bounds__(256) void transpose_w4(
    const float* __restrict__ w, float* __restrict__ wt, int IC9) {
  const int idx = blockIdx.x * 256 + threadIdx.x;   // qrow*64 + oc
  const int qrow = idx >> 6;
  const int oc = idx & 63;
  const float4 v = *(const float4*)&w[(size_t)oc * IC9 + qrow * 4];
  wt[(size_t)(qrow * 4 + 0) * 64 + oc] = v.x;
  wt[(size_t)(qrow * 4 + 1) * 64 + oc] = v.y;
  wt[(size_t)(qrow * 4 + 2) * 64 + oc] = v.z;
  wt[(size_t)(qrow * 4 + 3) * 64 + oc] = v.w;
}

// ---------------------------------------------------------------------------
// conv3x3 (pad 1) + inference BN + ReLU.  x:[32,IC,64,64] wt:[(IC*9)][64]
// out:[32,64,64,64].
// Round-10: round-9 structure (1024 blocks, 8 waves, 4 ocs/wave) with the
// launch_bounds clamp REVERTED to (512,4). Round-9's (512,8) forced
// VGPR 48->32 and spilled pre/acc to scratch: WRITE_SIZE 32MB->9.9GB,
// dur 436->4395us. Occupancy is set by min(grid, LDS, ACTUAL vgpr):
// at VGPR<=64 the HW already fits 8 waves/SIMD (m69 step) — the clamp
// was never needed; the grid (4 blocks/CU) is what unlocks occupancy.
// Grid: 32 b x 16 tiles x 2 oc-groups = 1024 blocks = 4 blocks/CU.
// Block: 512 threads = 8 waves; wave w in oc-group g owns ocs
// [g*32+4w, g*32+4w+4). Weight float4 -> 16 fma (intensity from round-7).
// oc-group is the TOP blockIdx bit: same-tile pairs are 512 apart = same
// XCD (512%8==0) -> L2 reuse of the duplicated x staging.
// Lane: r = lane&7 (row), lc = (lane>>3)*4. Row stride 36 floats:
// ds_read_b128 at the 8-bank-cycle wave64 minimum (b64 tail 2x-aliased,
// ~25% of a non-critical pipe — revisit only if LDS becomes the wall).
// Staging: wave w stages ic=w; lanes 0..33 cover the 34-col halo.
// Register prefetch of next icb + LDS double buffer, ONE barrier per icb.
// Accumulation order per output element: (icb, ic, ky, kx) — identical to
// all previous rounds => bit-identical numerics.
// ---------------------------------------------------------------------------
template <int IC>
__global__ __launch_bounds__(512, 4) void conv3x3_bn_relu(
    const float* __restrict__ x, const float* __restrict__ wt,
    const float* __restrict__ g, const float* __restrict__ bb,
    const float* __restrict__ m, const float* __restrict__ vv,
    float* __restrict__ out) {
  __shared__ float xs[2][8][10][36];   // dbuf x 8 ic x 10 halo rows x 36 cols (34 used)

  const int tid = threadIdx.x;
  const int blk = blockIdx.x;
  const int ocg = blk >> 9;          // oc-group 0..1 (top bit)
  const int b = (blk >> 4) & 31;
  const int tile = blk & 15;
  const int by = (tile >> 1) << 3;   // 8-row tile
  const int bx = (tile & 1) << 5;    // 32-col tile
  const int wv = __builtin_amdgcn_readfirstlane(tid >> 6);  // wave id 0..7
  const int lane = tid & 63;
  const int r = lane & 7;            // output row in tile
  const int lc = (lane >> 3) << 2;   // 0,4,..,28 col base (4 px)
  const int ocbase = (ocg << 5) + (wv << 2);  // wave-uniform oc base (4 ocs)

  // input staging decomposition: wave wv stages ic=wv, lanes 0..33 = cols
  const int sic = wv;
  const int sc = lane;               // halo col 0..33 active
  const int gx = bx + sc - 1;
  const bool cok = (sc < 34) && (gx >= 0) && (gx < 64);

  float acc[4][4];
#pragma unroll
  for (int p = 0; p < 4; ++p)
#pragma unroll
    for (int o = 0; o < 4; ++o) acc[p][o] = 0.0f;

  float pre[10];
  // ---- prologue: load + stage icb=0 into buffer 0 ----
  {
    const float* xp = x + ((size_t)b * IC + sic) * 4096;
#pragma unroll
    for (int rr = 0; rr < 10; ++rr) {
      const int gy = by + rr - 1;
      pre[rr] = 0.0f;
      if (cok && gy >= 0 && gy < 64) pre[rr] = xp[gy * 64 + gx];
    }
#pragma unroll
    for (int rr = 0; rr < 10; ++rr)
      if (sc < 34) xs[0][sic][rr][sc] = pre[rr];
  }
  __syncthreads();

  int cur = 0;
  for (int icb = 0; icb < IC; icb += 8) {
    const bool has_next = (icb + 8) < IC;
    // ---- issue next-icb global loads early (hidden under compute) ----
    if (has_next) {
      const float* xp = x + ((size_t)b * IC + icb + 8 + sic) * 4096;
#pragma unroll
      for (int rr = 0; rr < 10; ++rr) {
        const int gy = by + rr - 1;
        pre[rr] = 0.0f;
        if (cok && gy >= 0 && gy < 64) pre[rr] = xp[gy * 64 + gx];
      }
    }

    // ---- compute from current buffer ----
    const float* wbase = wt + (size_t)icb * 9 * 64 + ocbase;  // uniform
    for (int ic = 0; ic < 8; ++ic) {
#pragma unroll
      for (int ky = 0; ky < 3; ++ky) {
        float xv[6];
        *(float4*)&xv[0] = *(const float4*)&xs[cur][ic][r + ky][lc];
        *(float2*)&xv[4] = *(const float2*)&xs[cur][ic][r + ky][lc + 4];
#pragma unroll
        for (int kx = 0; kx < 3; ++kx) {
          // wave-uniform address -> s_load into SGPRs
          const float4 w4 = *(const float4*)(wbase + (ic * 9 + ky * 3 + kx) * 64);
#pragma unroll
          for (int p = 0; p < 4; ++p) {
            acc[p][0] = fmaf(xv[kx + p], w4.x, acc[p][0]);
            acc[p][1] = fmaf(xv[kx + p], w4.y, acc[p][1]);
            acc[p][2] = fmaf(xv[kx + p], w4.z, acc[p][2]);
            acc[p][3] = fmaf(xv[kx + p], w4.w, acc[p][3]);
          }
        }
      }
    }

    // ---- write prefetched tile into the other buffer, single barrier ----
    if (has_next) {
#pragma unroll
      for (int rr = 0; rr < 10; ++rr)
        if (sc < 34) xs[cur ^ 1][sic][rr][sc] = pre[rr];
    }
    __syncthreads();
    cur ^= 1;
  }

  // ---- epilogue: BN + ReLU + float4 store ----
#pragma unroll
  for (int o = 0; o < 4; ++o) {
    const int oc = ocbase + o;
    const float sc2 = g[oc] * (1.0f / sqrtf(vv[oc] + 1e-5f));
    const float sh = bb[oc] - m[oc] * sc2;
    float4 v;
    v.x = fmaxf(fmaf(acc[0][o], sc2, sh), 0.0f);
    v.y = fmaxf(fmaf(acc[1][o], sc2, sh), 0.0f);
    v.z = fmaxf(fmaf(acc[2][o], sc2, sh), 0.0f);
    v.w = fmaxf(fmaf(acc[3][o], sc2, sh), 0.0f);
    *(float4*)&out[(((size_t)b * 64 + oc) * 64 + (by + r)) * 64 + bx + lc] = v;
  }
}

// ---------------------------------------------------------------------------
// 1x1 conv (64->1) + bias into lg64[32][4096].  Grid 32*16 blocks.
// ---------------------------------------------------------------------------
__global__ __launch_bounds__(256) void logits64_k(
    const float* __restrict__ h2, const float* __restrict__ w3,
    const float* __restrict__ b3, float* __restrict__ lg64) {
  const int blk = blockIdx.x;
  const int b = blk >> 4;
  const int p = ((blk & 15) << 8) + threadIdx.x;
  __shared__ float wvv[64];
  if (threadIdx.x < 64) wvv[threadIdx.x] = w3[threadIdx.x];
  __syncthreads();
  float s = b3[0];
  const float* hp = h2 + (size_t)b * 64 * 4096 + p;
  for (int oc = 0; oc < 64; ++oc)
    s = fmaf(hp[(size_t)oc * 4096], wvv[oc], s);
  lg64[b * 4096 + p] = s;
}

// ---------------------------------------------------------------------------
// bilinear 64->256 (half-pixel, edge clamp) + sigmoid.
// ---------------------------------------------------------------------------
__global__ __launch_bounds__(256) void upsample_k(
    const float* __restrict__ lg64, float* __restrict__ logits,
    float* __restrict__ heat) {
  const int blk = blockIdx.x;
  const int b = blk >> 6;
  const int qq = ((blk & 63) << 10) + (threadIdx.x << 2);
  const float* lg = lg64 + b * 4096;
  const int oy = qq >> 8;
  const float sy = (float)oy * 0.25f - 0.375f;
  const float fy = floorf(sy);
  const int y0 = (int)fy;
  const float ty = sy - fy;
  const int y0c = y0 < 0 ? 0 : y0;
  const int y1c = (y0 + 1) > 63 ? 63 : (y0 + 1);
  const float* r0 = lg + y0c * 64;
  const float* r1 = lg + y1c * 64;
  float4 lo, he;
  float* lop = (float*)&lo;
  float* hep = (float*)&he;
#pragma unroll
  for (int j = 0; j < 4; ++j) {
    const int ox = (qq & 255) + j;
    const float sx = (float)ox * 0.25f - 0.375f;
    const float fx = floorf(sx);
    const int x0 = (int)fx;
    const float tx = sx - fx;
    const int x0c = x0 < 0 ? 0 : x0;
    const int x1c = (x0 + 1) > 63 ? 63 : (x0 + 1);
    const float v00 = r0[x0c], v01 = r0[x1c];
    const float v10 = r1[x0c], v11 = r1[x1c];
    const float vtop = v00 + (v01 - v00) * tx;
    const float vbot = v10 + (v11 - v10) * tx;
    const float val = vtop + (vbot - vtop) * ty;
    lop[j] = val;
    hep[j] = 1.0f / (1.0f + expf(-val));
  }
  const size_t o = (size_t)b * 65536 + qq;
  *(float4*)(logits + o) = lo;
  *(float4*)(heat + o) = he;
}

// ---------------------------------------------------------------------------
// Positive points, phase 1: per-stripe 9x9 NMS peak top3 + stripe argmax.
// ---------------------------------------------------------------------------
__global__ __launch_bounds__(256) void pos_stripe(
    const float* __restrict__ heat, float* __restrict__ cand) {
  const int b = blockIdx.x >> 4;
  const int stripe = blockIdx.x & 15;
  const int y0 = stripe << 4;
  const float* s = heat + (size_t)b * 65536;
  const int tid = threadIdx.x;
  __shared__ float sm[24][256];
  __shared__ float rm[24][256];
  __shared__ float rv[256 * 3];
  __shared__ int ri[256 * 3];
  __shared__ float mvv[256];
  __shared__ int mii[256];
  __shared__ float rv2[24];
  __shared__ int ri2[24];
  __shared__ float mv2[8];
  __shared__ int mi2[8];

  for (int l = tid; l < 24 * 256; l += 256) {
    const int rr = l >> 8, xx = l & 255;
    const int gy = y0 - 4 + rr;
    sm[rr][xx] = (gy >= 0 && gy < 256) ? s[gy * 256 + xx] : NEG_INF;
  }
  __syncthreads();
  for (int l = tid; l < 24 * 256; l += 256) {
    const int rr = l >> 8, xx = l & 255;
    const int lo = (xx - 4 < 0) ? 0 : xx - 4;
    const int hi = (xx + 4 > 255) ? 255 : xx + 4;
    float mx = NEG_INF;
    for (int x2 = lo; x2 <= hi; ++x2) mx = fmaxf(mx, sm[rr][x2]);
    rm[rr][xx] = mx;
  }
  __syncthreads();

  float tv[3] = {NEG_INF, NEG_INF, NEG_INF};
  int ti[3] = {IDX_SENT, IDX_SENT, IDX_SENT};
  float bmax = NEG_INF;
  int bidx = IDX_SENT;
  for (int l = tid; l < 16 * 256; l += 256) {
    const int ry = l >> 8, xx = l & 255;
    const int lr = ry + 4;
    const float v = sm[lr][xx];
    float lm = rm[lr - 4][xx];
#pragma unroll
    for (int d = -3; d <= 4; ++d) lm = fmaxf(lm, rm[lr + d][xx]);
    const int gidx = (y0 + ry) * 256 + xx;
    if (v > bmax) { bmax = v; bidx = gidx; }
    if (v == lm && v > 0.1f) top3_insert(v, gidx, tv, ti);
  }

  rv[tid * 3 + 0] = tv[0]; rv[tid * 3 + 1] = tv[1]; rv[tid * 3 + 2] = tv[2];
  ri[tid * 3 + 0] = ti[0]; ri[tid * 3 + 1] = ti[1]; ri[tid * 3 + 2] = ti[2];
  mvv[tid] = bmax; mii[tid] = bidx;
  __syncthreads();

  if (tid < 8) {
    float av[3] = {NEG_INF, NEG_INF, NEG_INF};
    int ai[3] = {IDX_SENT, IDX_SENT, IDX_SENT};
    float am = NEG_INF; int amI = IDX_SENT;
    for (int t = tid * 32; t < tid * 32 + 32; ++t) {
      for (int k = 0; k < 3; ++k) top3_insert(rv[t * 3 + k], ri[t * 3 + k], av, ai);
      if (mvv[t] > am || (mvv[t] == am && mii[t] < amI)) { am = mvv[t]; amI = mii[t]; }
    }
    rv2[tid * 3 + 0] = av[0]; rv2[tid * 3 + 1] = av[1]; rv2[tid * 3 + 2] = av[2];
    ri2[tid * 3 + 0] = ai[0]; ri2[tid * 3 + 1] = ai[1]; ri2[tid * 3 + 2] = ai[2];
    mv2[tid] = am; mi2[tid] = amI;
  }
  __syncthreads();

  if (tid == 0) {
    float fv[3] = {NEG_INF, NEG_INF, NEG_INF};
    int fi[3] = {IDX_SENT, IDX_SENT, IDX_SENT};
    for (int t = 0; t < 24; ++t) top3_insert(rv2[t], ri2[t], fv, fi);
    float gbv = NEG_INF; int gbi = IDX_SENT;
    for (int t = 0; t < 8; ++t)
      if (mv2[t] > gbv || (mv2[t] == gbv && mi2[t] < gbi)) { gbv = mv2[t]; gbi = mi2[t]; }
    float* c = cand + ((size_t)b * 16 + stripe) * 8;
    c[0] = fv[0]; c[1] = __int_as_float(fi[0]);
    c[2] = fv[1]; c[3] = __int_as_float(fi[1]);
    c[4] = fv[2]; c[5] = __int_as_float(fi[2]);
    c[6] = gbv;   c[7] = __int_as_float(gbi);
  }
}

// ---------------------------------------------------------------------------
// Positive points, phase 2: reduce 16 stripe candidates -> final outputs.
// ---------------------------------------------------------------------------
__global__ void pos_final(const float* __restrict__ cand,
                          float* __restrict__ coords, float* __restrict__ labels) {
  const int b = blockIdx.x;
  if (threadIdx.x != 0) return;
  float fv[3] = {NEG_INF, NEG_INF, NEG_INF};
  int fi[3] = {IDX_SENT, IDX_SENT, IDX_SENT};
  float gbv = NEG_INF; int gbi = IDX_SENT;
  for (int st = 0; st < 16; ++st) {
    const float* c = cand + ((size_t)b * 16 + st) * 8;
    for (int k = 0; k < 3; ++k)
      top3_insert(c[2 * k], __float_as_int(c[2 * k + 1]), fv, fi);
    const float mv = c[6]; const int mi = __float_as_int(c[7]);
    if (mv > gbv || (mv == gbv && mi < gbi)) { gbv = mv; gbi = mi; }
  }
  float* co = coords + (size_t)b * 10;
  float* la = labels + (size_t)b * 5;
  const bool any_peak = (fi[0] != IDX_SENT);
  const int i0 = any_peak ? fi[0] : gbi;
  co[0] = (float)(i0 & 255);
  co[1] = (float)(i0 >> 8);
  la[0] = 1.0f;
  for (int k = 1; k < 3; ++k) {
    const bool valid = (fi[k] != IDX_SENT);
    co[k * 2 + 0] = valid ? (float)(fi[k] & 255) : 0.0f;
    co[k * 2 + 1] = valid ? (float)(fi[k] >> 8) : 0.0f;
    la[k] = valid ? 1.0f : -1.0f;
  }
}

// ---------------------------------------------------------------------------
// Negative points, phase 1: per-64px-chunk count of (heat<0.3) + partial max.
// ---------------------------------------------------------------------------
__global__ __launch_bounds__(256) void neg_count(
    const float* __restrict__ heat, float* __restrict__ ncnt,
    float* __restrict__ pmax) {
  const int blk = blockIdx.x;
  const int b = blk >> 2;
  const int part = blk & 3;
  const int tid = threadIdx.x;
  const int chunk = (part << 8) + tid;
  const float4* s = (const float4*)(heat + (size_t)b * 65536 + chunk * 64);
  int c = 0;
  float mx = NEG_INF;
  for (int i = 0; i < 16; ++i) {
    const float4 v = s[i];
    c += (v.x < 0.3f) + (v.y < 0.3f) + (v.z < 0.3f) + (v.w < 0.3f);
    mx = fmaxf(mx, fmaxf(fmaxf(v.x, v.y), fmaxf(v.z, v.w)));
  }
  ncnt[b * 1024 + chunk] = (float)c;
  __shared__ float mxs[256];
  mxs[tid] = mx;
  __syncthreads();
  if (tid == 0) {
    float gmx = NEG_INF;
    for (int t = 0; t < 256; ++t) gmx = fmaxf(gmx, mxs[t]);
    pmax[blk] = gmx;
  }
}

// ---------------------------------------------------------------------------
// Negative points, phase 2: prefix, PRNG rank select, rescan.
// ---------------------------------------------------------------------------
__global__ __launch_bounds__(256) void neg_select(
    const float* __restrict__ heat, const float* __restrict__ ncnt,
    const float* __restrict__ pmax, float* __restrict__ coords,
    float* __restrict__ labels) {
  const int b = blockIdx.x;
  const int tid = threadIdx.x;
  const float* s = heat + (size_t)b * 65536;
  __shared__ float cnt[1024];
  __shared__ float c256[256];
  __shared__ int pfx[257];
  __shared__ float thr_s;
  __shared__ int fb_s;
  __shared__ int n_s;
  __shared__ int ridx_s[2];

  for (int l = tid; l < 1024; l += 256) cnt[l] = ncnt[b * 1024 + l];
  __syncthreads();
  c256[tid] = cnt[4 * tid] + cnt[4 * tid + 1] + cnt[4 * tid + 2] + cnt[4 * tid + 3];
  __syncthreads();
  if (tid == 0) {
    int tot = 0;
    for (int t = 0; t < 256; ++t) tot += (int)c256[t];
    const float gm = fmaxf(fmaxf(pmax[b * 4], pmax[b * 4 + 1]),
                           fmaxf(pmax[b * 4 + 2], pmax[b * 4 + 3]));
    fb_s = (tot > 0) ? 0 : 1;
    thr_s = (tot > 0) ? 0.3f : gm;
  }
  __syncthreads();
  if (fb_s) {
    const float t2 = thr_s;
    const int base = tid * 256;
    int c = 0;
    for (int i = 0; i < 256; ++i) c += (s[base + i] < t2) ? 1 : 0;
    c256[tid] = (float)c;
    __syncthreads();
  }
  if (tid == 0) {
    int run = 0;
    for (int t = 0; t < 256; ++t) { pfx[t] = run; run += (int)c256[t]; }
    pfx[256] = run;
    const int n = run;
    n_s = n;
    uint32_t k0, k1, a0, a1;
    threefry2x32(0u, 42u, 0u, (uint32_t)b, &k0, &k1);
    threefry2x32(k0, k1, 0u, 0u, &a0, &a1);
    const uint32_t bits0 = a0 ^ a1;
    threefry2x32(k0, k1, 0u, 1u, &a0, &a1);
    const uint32_t bits1 = a0 ^ a1;
    const float u0 = bits_to_uniform(bits0);
    const float u1 = bits_to_uniform(bits1);
    const float nf = (float)(n > 1 ? n : 1);
    int r0 = (int)(u0 * nf);
    int r1 = (int)(u1 * nf);
    const int rmax = (n - 1 > 0) ? n - 1 : 0;
    ridx_s[0] = r0 < rmax ? r0 : rmax;
    ridx_s[1] = r1 < rmax ? r1 : rmax;
    labels[(size_t)b * 5 + 3] = 0.0f;
    labels[(size_t)b * 5 + 4] = 0.0f;
    if (n == 0) {
      coords[(size_t)b * 10 + 6] = 0.0f; coords[(size_t)b * 10 + 7] = 0.0f;
      coords[(size_t)b * 10 + 8] = 0.0f; coords[(size_t)b * 10 + 9] = 0.0f;
    }
  }
  __syncthreads();
  const int n = n_s;
  if (n > 0) {
    const float t2 = thr_s;
    const int p0 = pfx[tid], p1 = pfx[tid + 1];
    const int base = tid * 256;
    for (int j = 0; j < 2; ++j) {
      const int r = ridx_s[j];
      if (r >= p0 && r < p1) {
        int need = r - p0;
        int sel = -1;
        for (int i = 0; i < 256; ++i) {
          if (s[base + i] < t2) {
            if (need == 0) { sel = base + i; break; }
            --need;
          }
        }
        coords[(size_t)b * 10 + 6 + j * 2 + 0] = (float)(sel & 255);
        coords[(size_t)b * 10 + 6 + j * 2 + 1] = (float)(sel >> 8);
      }
    }
  }
}

// ---------------------------------------------------------------------------
extern "C" void kernel_launch(void* const* d_in, const int* in_sizes, int n_in,
                              void* d_out, int out_size, void* d_ws, size_t ws_size,
                              hipStream_t stream) {
  (void)in_sizes; (void)n_in; (void)out_size; (void)ws_size;
  const float* x  = (const float*)d_in[0];
  const float* w1 = (const float*)d_in[1];
  const float* g1 = (const float*)d_in[2];
  const float* b1 = (const float*)d_in[3];
  const float* m1 = (const float*)d_in[4];
  const float* v1 = (const float*)d_in[5];
  const float* w2 = (const float*)d_in[6];
  const float* g2 = (const float*)d_in[7];
  const float* b2 = (const float*)d_in[8];
  const float* m2 = (const float*)d_in[9];
  const float* v2 = (const float*)d_in[10];
  const float* w3 = (const float*)d_in[11];
  const float* b3 = (const float*)d_in[12];

  float* out = (float*)d_out;
  float* heat = out;                         // [32,1,256,256]
  float* coords = out + (size_t)32 * 65536;  // [32,1,5,2]
  float* labels = coords + 320;              // [32,1,5]
  float* logits = labels + 160;              // [32,1,256,256]

  // Transposed weights live in the logits region (overwritten by upsample_k
  // only after both convs have consumed them — stream-ordered, no hazard).
  float* w1t = logits;            // 256*9*64 floats
  float* w2t = logits + 147456;   // 64*9*64 floats

  float* h1 = (float*)d_ws;                        // [32,64,64,64]
  float* h2 = h1 + (size_t)32 * 64 * 64 * 64;      // [32,64,64,64]
  float* lg64 = h1;                                // reuse after conv2
  float* cand = h1 + 131072;
  float* ncnt = h1 + 135168;
  float* pmax = h1 + 167936;

  transpose_w4<<<144, 256, 0, stream>>>(w1, w1t, 2304);
  transpose_w4<<<36, 256, 0, stream>>>(w2, w2t, 576);
  conv3x3_bn_relu<256><<<1024, 512, 0, stream>>>(x, w1t, g1, b1, m1, v1, h1);
  conv3x3_bn_relu<64><<<1024, 512, 0, stream>>>(h1, w2t, g2, b2, m2, v2, h2);
  logits64_k<<<512, 256, 0, stream>>>(h2, w3, b3, lg64);
  upsample_k<<<2048, 256, 0, stream>>>(lg64, logits, heat);
  pos_stripe<<<512, 256, 0, stream>>>(heat, cand);
  pos_final<<<32, 64, 0, stream>>>(cand, coords, labels);
  neg_count<<<128, 256, 0, stream>>>(heat, ncnt, pmax);
  neg_select<<<32, 256, 0, stream>>>(heat, ncnt, pmax, coords, labels);
}

// Round 5
// 830.788 us; speedup vs baseline: 6.8295x; 3.8726x over previous
//
#include <hip/hip_runtime.h>
#include <stdint.h>
#include <math.h>

#define NEG_INF (-__builtin_inff())
#define IDX_SENT 0x7fffffff

typedef __attribute__((address_space(1))) const void gas_t;   // global
typedef __attribute__((address_space(3))) void las_t;         // LDS

// ---------------------------------------------------------------------------
// JAX threefry2x32 (20 rounds), exact replication.
// ---------------------------------------------------------------------------
__device__ __forceinline__ void threefry2x32(uint32_t k0, uint32_t k1,
                                             uint32_t x0, uint32_t x1,
                                             uint32_t* o0, uint32_t* o1) {
  const uint32_t ks2 = k0 ^ k1 ^ 0x1BD11BDAu;
  uint32_t ks[3] = {k0, k1, ks2};
  const int rot[2][4] = {{13, 15, 26, 6}, {17, 29, 16, 24}};
  x0 += ks[0];
  x1 += ks[1];
#pragma unroll
  for (int i = 0; i < 5; ++i) {
#pragma unroll
    for (int j = 0; j < 4; ++j) {
      const int r = rot[i & 1][j];
      x0 += x1;
      x1 = (x1 << r) | (x1 >> (32 - r));
      x1 ^= x0;
    }
    x0 += ks[(i + 1) % 3];
    x1 += ks[(i + 2) % 3] + (uint32_t)(i + 1);
  }
  *o0 = x0;
  *o1 = x1;
}

__device__ __forceinline__ float bits_to_uniform(uint32_t bits) {
  return __uint_as_float((bits >> 9) | 0x3f800000u) - 1.0f;
}

// top3 ordered by (value desc, index asc) — matches jax.lax.top_k tie-break.
__device__ __forceinline__ void top3_insert(float v, int idx, float tv[3], int ti[3]) {
  if ((v > tv[2]) || (v == tv[2] && idx < ti[2])) {
    tv[2] = v; ti[2] = idx;
    if ((tv[2] > tv[1]) || (tv[2] == tv[1] && ti[2] < ti[1])) {
      float fv = tv[1]; int fi = ti[1];
      tv[1] = tv[2]; ti[1] = ti[2];
      tv[2] = fv;     ti[2] = fi;
      if ((tv[1] > tv[0]) || (tv[1] == tv[0] && ti[1] < ti[0])) {
        fv = tv[0]; fi = ti[0];
        tv[0] = tv[1]; ti[0] = ti[1];
        tv[1] = fv;    ti[1] = fi;
      }
    }
  }
}

// ---------------------------------------------------------------------------
// Weight transpose: w[oc][IC][3][3] -> wt[(ic*9+k)][64].
// ---------------------------------------------------------------------------
__global__ __launch_bounds__(256) void transpose_w4(
    const float* __restrict__ w, float* __restrict__ wt, int IC9) {
  const int idx = blockIdx.x * 256 + threadIdx.x;   // qrow*64 + oc
  const int qrow = idx >> 6;
  const int oc = idx & 63;
  const float4 v = *(const float4*)&w[(size_t)oc * IC9 + qrow * 4];
  wt[(size_t)(qrow * 4 + 0) * 64 + oc] = v.x;
  wt[(size_t)(qrow * 4 + 1) * 64 + oc] = v.y;
  wt[(size_t)(qrow * 4 + 2) * 64 + oc] = v.z;
  wt[(size_t)(qrow * 4 + 3) * 64 + oc] = v.w;
}

// ---------------------------------------------------------------------------
// conv3x3 (pad 1) + inference BN + ReLU.  x:[32,IC,64,64] wt:[(IC*9)][64]
// out:[32,64,64,64].
// Round-11 (post-spill-diagnosis):
//  * Rounds 3/4 showed hipcc treats launch_bounds(512,N) as min-BLOCKS/CU:
//    VGPR cap = 2048/(8N) -> (512,8)=32, (512,4)=64; both spilled (WRITE
//    9.9/4.9 GB). Use (512,3): cap >=85 under either semantics = spill-proof;
//    actual occupancy then comes from real VGPR count (target <=64 -> grid's
//    4 blocks/CU = 32 waves/CU).
//  * Register staging (pre[10]) replaced by __builtin_amdgcn_global_load_lds
//    DMA: zero VGPR round-trip, no ds_writes. LDS dest is wave-uniform row
//    base + lane*4B (the required contiguous-lane layout). Halo pads: LDS is
//    zeroed ONCE up front; invalid rows (uniform branch) and invalid cols
//    (exec-masked lanes) are simply never DMA'd -> stay 0 across all icbs
//    (validity is per-block-constant). Compiler emits vmcnt(0) before
//    s_barrier -> the single barrier per icb drains the DMA.
//  * Wave shape 2 px x 8 oc (acc[2][8]=16 regs, round-2's codegen family):
//    8192 waves = 32 waves/CU; LDS reads = 2x ds_read_b64 per (ic,ky) per
//    48 fma -> LDS pipe ~53% at full occupancy (4-way bank alias budgeted).
// Grid: 32 b x 16 tiles x 2 oc-groups = 1024 blocks = 4 blocks/CU.
// Block: 512 thr = 8 waves; wave wv: rowhalf=wv&1, ocset=wv>>1;
//   ocbase = ocg*32 + ocset*8 (wave-uniform -> s_load weights).
// Lane: r = (lane&3)|(rowhalf<<2), lc = (lane>>2)*2.
// Accumulation order per output element: (icb, ic, ky, kx) — identical to
// all previous rounds => bit-identical numerics.
// ---------------------------------------------------------------------------
template <int IC>
__global__ __launch_bounds__(512, 3) void conv3x3_bn_relu(
    const float* __restrict__ x, const float* __restrict__ wt,
    const float* __restrict__ g, const float* __restrict__ bb,
    const float* __restrict__ m, const float* __restrict__ vv,
    float* __restrict__ out) {
  __shared__ float xs[2][8][10][36];   // dbuf x 8 ic x 10 halo rows x 36 cols (34 used)

  const int tid = threadIdx.x;
  const int blk = blockIdx.x;
  const int ocg = blk >> 9;          // oc-group 0..1 (top bit)
  const int b = (blk >> 4) & 31;
  const int tile = blk & 15;
  const int by = (tile >> 1) << 3;   // 8-row tile
  const int bx = (tile & 1) << 5;    // 32-col tile
  const int wv = __builtin_amdgcn_readfirstlane(tid >> 6);  // wave id 0..7
  const int lane = tid & 63;
  const int rh = wv & 1;             // row half (wave-uniform)
  const int os = wv >> 1;            // oc set 0..3 (wave-uniform)
  const int r = (lane & 3) | (rh << 2);   // output row 0..7
  const int lc = (lane >> 2) << 1;        // col base 0,2,..,30 (2 px)
  const int ocbase = (ocg << 5) | (os << 3);  // wave-uniform, 8 ocs

  // staging decomposition: wave wv DMAs ic=wv, lanes 0..33 = halo cols
  const int sc = lane;
  const int gx = bx + sc - 1;
  const bool cok = (sc < 34) && (gx >= 0) && (gx < 64);

  float acc[2][8];
#pragma unroll
  for (int p = 0; p < 2; ++p)
#pragma unroll
    for (int o = 0; o < 8; ++o) acc[p][o] = 0.0f;

  // ---- zero LDS once: never-DMA'd halo cells must read as 0 ----
  for (int l = tid; l < 2 * 8 * 10 * 36; l += 512)
    (&xs[0][0][0][0])[l] = 0.0f;
  __syncthreads();

  // DMA one icb (8 ics, wave wv handles ic icb0+wv) into buffer `buf`.
  auto stage = [&](int buf, int icb0) {
    if (cok) {
      const float* gb = x + ((size_t)b * IC + icb0 + wv) * 4096 + (by - 1) * 64 + gx;
#pragma unroll
      for (int rr = 0; rr < 10; ++rr) {
        const int gy = by + rr - 1;
        if (gy >= 0 && gy < 64) {
          __builtin_amdgcn_global_load_lds(
              (gas_t*)(const void*)(gb + rr * 64),
              (las_t*)(void*)(&xs[buf][wv][rr][0]),
              4, 0, 0);
        }
      }
    }
  };

  // ---- prologue: DMA icb=0 into buffer 0 ----
  stage(0, 0);
  __syncthreads();

  int cur = 0;
  for (int icb = 0; icb < IC; icb += 8) {
    // issue next-icb DMA early; completes under compute, drained at barrier
    if (icb + 8 < IC) stage(cur ^ 1, icb + 8);

    // ---- compute from current buffer ----
    const float* wbase = wt + (size_t)icb * 9 * 64 + ocbase;  // uniform
    for (int ic = 0; ic < 8; ++ic) {
#pragma unroll
      for (int ky = 0; ky < 3; ++ky) {
        float xv[4];
        *(float2*)&xv[0] = *(const float2*)&xs[cur][ic][r + ky][lc];
        *(float2*)&xv[2] = *(const float2*)&xs[cur][ic][r + ky][lc + 2];
#pragma unroll
        for (int kx = 0; kx < 3; ++kx) {
          // wave-uniform address -> s_load into SGPRs
          const float4* wp4 = (const float4*)(wbase + (ic * 9 + ky * 3 + kx) * 64);
#pragma unroll
          for (int q = 0; q < 2; ++q) {
            const float4 w4 = wp4[q];
#pragma unroll
            for (int p = 0; p < 2; ++p) {
              acc[p][4 * q + 0] = fmaf(xv[kx + p], w4.x, acc[p][4 * q + 0]);
              acc[p][4 * q + 1] = fmaf(xv[kx + p], w4.y, acc[p][4 * q + 1]);
              acc[p][4 * q + 2] = fmaf(xv[kx + p], w4.z, acc[p][4 * q + 2]);
              acc[p][4 * q + 3] = fmaf(xv[kx + p], w4.w, acc[p][4 * q + 3]);
            }
          }
        }
      }
    }
    __syncthreads();
    cur ^= 1;
  }

  // ---- epilogue: BN + ReLU + float2 store ----
#pragma unroll
  for (int o = 0; o < 8; ++o) {
    const int oc = ocbase + o;
    const float sc2 = g[oc] * (1.0f / sqrtf(vv[oc] + 1e-5f));
    const float sh = bb[oc] - m[oc] * sc2;
    float2 v;
    v.x = fmaxf(fmaf(acc[0][o], sc2, sh), 0.0f);
    v.y = fmaxf(fmaf(acc[1][o], sc2, sh), 0.0f);
    *(float2*)&out[(((size_t)b * 64 + oc) * 64 + (by + r)) * 64 + bx + lc] = v;
  }
}

// ---------------------------------------------------------------------------
// 1x1 conv (64->1) + bias into lg64[32][4096].  Grid 32*16 blocks.
// ---------------------------------------------------------------------------
__global__ __launch_bounds__(256) void logits64_k(
    const float* __restrict__ h2, const float* __restrict__ w3,
    const float* __restrict__ b3, float* __restrict__ lg64) {
  const int blk = blockIdx.x;
  const int b = blk >> 4;
  const int p = ((blk & 15) << 8) + threadIdx.x;
  __shared__ float wvv[64];
  if (threadIdx.x < 64) wvv[threadIdx.x] = w3[threadIdx.x];
  __syncthreads();
  float s = b3[0];
  const float* hp = h2 + (size_t)b * 64 * 4096 + p;
  for (int oc = 0; oc < 64; ++oc)
    s = fmaf(hp[(size_t)oc * 4096], wvv[oc], s);
  lg64[b * 4096 + p] = s;
}

// ---------------------------------------------------------------------------
// bilinear 64->256 (half-pixel, edge clamp) + sigmoid.
// ---------------------------------------------------------------------------
__global__ __launch_bounds__(256) void upsample_k(
    const float* __restrict__ lg64, float* __restrict__ logits,
    float* __restrict__ heat) {
  const int blk = blockIdx.x;
  const int b = blk >> 6;
  const int qq = ((blk & 63) << 10) + (threadIdx.x << 2);
  const float* lg = lg64 + b * 4096;
  const int oy = qq >> 8;
  const float sy = (float)oy * 0.25f - 0.375f;
  const float fy = floorf(sy);
  const int y0 = (int)fy;
  const float ty = sy - fy;
  const int y0c = y0 < 0 ? 0 : y0;
  const int y1c = (y0 + 1) > 63 ? 63 : (y0 + 1);
  const float* r0 = lg + y0c * 64;
  const float* r1 = lg + y1c * 64;
  float4 lo, he;
  float* lop = (float*)&lo;
  float* hep = (float*)&he;
#pragma unroll
  for (int j = 0; j < 4; ++j) {
    const int ox = (qq & 255) + j;
    const float sx = (float)ox * 0.25f - 0.375f;
    const float fx = floorf(sx);
    const int x0 = (int)fx;
    const float tx = sx - fx;
    const int x0c = x0 < 0 ? 0 : x0;
    const int x1c = (x0 + 1) > 63 ? 63 : (x0 + 1);
    const float v00 = r0[x0c], v01 = r0[x1c];
    const float v10 = r1[x0c], v11 = r1[x1c];
    const float vtop = v00 + (v01 - v00) * tx;
    const float vbot = v10 + (v11 - v10) * tx;
    const float val = vtop + (vbot - vtop) * ty;
    lop[j] = val;
    hep[j] = 1.0f / (1.0f + expf(-val));
  }
  const size_t o = (size_t)b * 65536 + qq;
  *(float4*)(logits + o) = lo;
  *(float4*)(heat + o) = he;
}

// ---------------------------------------------------------------------------
// Positive points, phase 1: per-stripe 9x9 NMS peak top3 + stripe argmax.
// ---------------------------------------------------------------------------
__global__ __launch_bounds__(256) void pos_stripe(
    const float* __restrict__ heat, float* __restrict__ cand) {
  const int b = blockIdx.x >> 4;
  const int stripe = blockIdx.x & 15;
  const int y0 = stripe << 4;
  const float* s = heat + (size_t)b * 65536;
  const int tid = threadIdx.x;
  __shared__ float sm[24][256];
  __shared__ float rm[24][256];
  __shared__ float rv[256 * 3];
  __shared__ int ri[256 * 3];
  __shared__ float mvv[256];
  __shared__ int mii[256];
  __shared__ float rv2[24];
  __shared__ int ri2[24];
  __shared__ float mv2[8];
  __shared__ int mi2[8];

  for (int l = tid; l < 24 * 256; l += 256) {
    const int rr = l >> 8, xx = l & 255;
    const int gy = y0 - 4 + rr;
    sm[rr][xx] = (gy >= 0 && gy < 256) ? s[gy * 256 + xx] : NEG_INF;
  }
  __syncthreads();
  for (int l = tid; l < 24 * 256; l += 256) {
    const int rr = l >> 8, xx = l & 255;
    const int lo = (xx - 4 < 0) ? 0 : xx - 4;
    const int hi = (xx + 4 > 255) ? 255 : xx + 4;
    float mx = NEG_INF;
    for (int x2 = lo; x2 <= hi; ++x2) mx = fmaxf(mx, sm[rr][x2]);
    rm[rr][xx] = mx;
  }
  __syncthreads();

  float tv[3] = {NEG_INF, NEG_INF, NEG_INF};
  int ti[3] = {IDX_SENT, IDX_SENT, IDX_SENT};
  float bmax = NEG_INF;
  int bidx = IDX_SENT;
  for (int l = tid; l < 16 * 256; l += 256) {
    const int ry = l >> 8, xx = l & 255;
    const int lr = ry + 4;
    const float v = sm[lr][xx];
    float lm = rm[lr - 4][xx];
#pragma unroll
    for (int d = -3; d <= 4; ++d) lm = fmaxf(lm, rm[lr + d][xx]);
    const int gidx = (y0 + ry) * 256 + xx;
    if (v > bmax) { bmax = v; bidx = gidx; }
    if (v == lm && v > 0.1f) top3_insert(v, gidx, tv, ti);
  }

  rv[tid * 3 + 0] = tv[0]; rv[tid * 3 + 1] = tv[1]; rv[tid * 3 + 2] = tv[2];
  ri[tid * 3 + 0] = ti[0]; ri[tid * 3 + 1] = ti[1]; ri[tid * 3 + 2] = ti[2];
  mvv[tid] = bmax; mii[tid] = bidx;
  __syncthreads();

  if (tid < 8) {
    float av[3] = {NEG_INF, NEG_INF, NEG_INF};
    int ai[3] = {IDX_SENT, IDX_SENT, IDX_SENT};
    float am = NEG_INF; int amI = IDX_SENT;
    for (int t = tid * 32; t < tid * 32 + 32; ++t) {
      for (int k = 0; k < 3; ++k) top3_insert(rv[t * 3 + k], ri[t * 3 + k], av, ai);
      if (mvv[t] > am || (mvv[t] == am && mii[t] < amI)) { am = mvv[t]; amI = mii[t]; }
    }
    rv2[tid * 3 + 0] = av[0]; rv2[tid * 3 + 1] = av[1]; rv2[tid * 3 + 2] = av[2];
    ri2[tid * 3 + 0] = ai[0]; ri2[tid * 3 + 1] = ai[1]; ri2[tid * 3 + 2] = ai[2];
    mv2[tid] = am; mi2[tid] = amI;
  }
  __syncthreads();

  if (tid == 0) {
    float fv[3] = {NEG_INF, NEG_INF, NEG_INF};
    int fi[3] = {IDX_SENT, IDX_SENT, IDX_SENT};
    for (int t = 0; t < 24; ++t) top3_insert(rv2[t], ri2[t], fv, fi);
    float gbv = NEG_INF; int gbi = IDX_SENT;
    for (int t = 0; t < 8; ++t)
      if (mv2[t] > gbv || (mv2[t] == gbv && mi2[t] < gbi)) { gbv = mv2[t]; gbi = mi2[t]; }
    float* c = cand + ((size_t)b * 16 + stripe) * 8;
    c[0] = fv[0]; c[1] = __int_as_float(fi[0]);
    c[2] = fv[1]; c[3] = __int_as_float(fi[1]);
    c[4] = fv[2]; c[5] = __int_as_float(fi[2]);
    c[6] = gbv;   c[7] = __int_as_float(gbi);
  }
}

// ---------------------------------------------------------------------------
// Positive points, phase 2: reduce 16 stripe candidates -> final outputs.
// ---------------------------------------------------------------------------
__global__ void pos_final(const float* __restrict__ cand,
                          float* __restrict__ coords, float* __restrict__ labels) {
  const int b = blockIdx.x;
  if (threadIdx.x != 0) return;
  float fv[3] = {NEG_INF, NEG_INF, NEG_INF};
  int fi[3] = {IDX_SENT, IDX_SENT, IDX_SENT};
  float gbv = NEG_INF; int gbi = IDX_SENT;
  for (int st = 0; st < 16; ++st) {
    const float* c = cand + ((size_t)b * 16 + st) * 8;
    for (int k = 0; k < 3; ++k)
      top3_insert(c[2 * k], __float_as_int(c[2 * k + 1]), fv, fi);
    const float mv = c[6]; const int mi = __float_as_int(c[7]);
    if (mv > gbv || (mv == gbv && mi < gbi)) { gbv = mv; gbi = mi; }
  }
  float* co = coords + (size_t)b * 10;
  float* la = labels + (size_t)b * 5;
  const bool any_peak = (fi[0] != IDX_SENT);
  const int i0 = any_peak ? fi[0] : gbi;
  co[0] = (float)(i0 & 255);
  co[1] = (float)(i0 >> 8);
  la[0] = 1.0f;
  for (int k = 1; k < 3; ++k) {
    const bool valid = (fi[k] != IDX_SENT);
    co[k * 2 + 0] = valid ? (float)(fi[k] & 255) : 0.0f;
    co[k * 2 + 1] = valid ? (float)(fi[k] >> 8) : 0.0f;
    la[k] = valid ? 1.0f : -1.0f;
  }
}

// ---------------------------------------------------------------------------
// Negative points, phase 1: per-64px-chunk count of (heat<0.3) + partial max.
// ---------------------------------------------------------------------------
__global__ __launch_bounds__(256) void neg_count(
    const float* __restrict__ heat, float* __restrict__ ncnt,
    float* __restrict__ pmax) {
  const int blk = blockIdx.x;
  const int b = blk >> 2;
  const int part = blk & 3;
  const int tid = threadIdx.x;
  const int chunk = (part << 8) + tid;
  const float4* s = (const float4*)(heat + (size_t)b * 65536 + chunk * 64);
  int c = 0;
  float mx = NEG_INF;
  for (int i = 0; i < 16; ++i) {
    const float4 v = s[i];
    c += (v.x < 0.3f) + (v.y < 0.3f) + (v.z < 0.3f) + (v.w < 0.3f);
    mx = fmaxf(mx, fmaxf(fmaxf(v.x, v.y), fmaxf(v.z, v.w)));
  }
  ncnt[b * 1024 + chunk] = (float)c;
  __shared__ float mxs[256];
  mxs[tid] = mx;
  __syncthreads();
  if (tid == 0) {
    float gmx = NEG_INF;
    for (int t = 0; t < 256; ++t) gmx = fmaxf(gmx, mxs[t]);
    pmax[blk] = gmx;
  }
}

// ---------------------------------------------------------------------------
// Negative points, phase 2: prefix, PRNG rank select, rescan.
// ---------------------------------------------------------------------------
__global__ __launch_bounds__(256) void neg_select(
    const float* __restrict__ heat, const float* __restrict__ ncnt,
    const float* __restrict__ pmax, float* __restrict__ coords,
    float* __restrict__ labels) {
  const int b = blockIdx.x;
  const int tid = threadIdx.x;
  const float* s = heat + (size_t)b * 65536;
  __shared__ float cnt[1024];
  __shared__ float c256[256];
  __shared__ int pfx[257];
  __shared__ float thr_s;
  __shared__ int fb_s;
  __shared__ int n_s;
  __shared__ int ridx_s[2];

  for (int l = tid; l < 1024; l += 256) cnt[l] = ncnt[b * 1024 + l];
  __syncthreads();
  c256[tid] = cnt[4 * tid] + cnt[4 * tid + 1] + cnt[4 * tid + 2] + cnt[4 * tid + 3];
  __syncthreads();
  if (tid == 0) {
    int tot = 0;
    for (int t = 0; t < 256; ++t) tot += (int)c256[t];
    const float gm = fmaxf(fmaxf(pmax[b * 4], pmax[b * 4 + 1]),
                           fmaxf(pmax[b * 4 + 2], pmax[b * 4 + 3]));
    fb_s = (tot > 0) ? 0 : 1;
    thr_s = (tot > 0) ? 0.3f : gm;
  }
  __syncthreads();
  if (fb_s) {
    const float t2 = thr_s;
    const int base = tid * 256;
    int c = 0;
    for (int i = 0; i < 256; ++i) c += (s[base + i] < t2) ? 1 : 0;
    c256[tid] = (float)c;
    __syncthreads();
  }
  if (tid == 0) {
    int run = 0;
    for (int t = 0; t < 256; ++t) { pfx[t] = run; run += (int)c256[t]; }
    pfx[256] = run;
    const int n = run;
    n_s = n;
    uint32_t k0, k1, a0, a1;
    threefry2x32(0u, 42u, 0u, (uint32_t)b, &k0, &k1);
    threefry2x32(k0, k1, 0u, 0u, &a0, &a1);
    const uint32_t bits0 = a0 ^ a1;
    threefry2x32(k0, k1, 0u, 1u, &a0, &a1);
    const uint32_t bits1 = a0 ^ a1;
    const float u0 = bits_to_uniform(bits0);
    const float u1 = bits_to_uniform(bits1);
    const float nf = (float)(n > 1 ? n : 1);
    int r0 = (int)(u0 * nf);
    int r1 = (int)(u1 * nf);
    const int rmax = (n - 1 > 0) ? n - 1 : 0;
    ridx_s[0] = r0 < rmax ? r0 : rmax;
    ridx_s[1] = r1 < rmax ? r1 : rmax;
    labels[(size_t)b * 5 + 3] = 0.0f;
    labels[(size_t)b * 5 + 4] = 0.0f;
    if (n == 0) {
      coords[(size_t)b * 10 + 6] = 0.0f; coords[(size_t)b * 10 + 7] = 0.0f;
      coords[(size_t)b * 10 + 8] = 0.0f; coords[(size_t)b * 10 + 9] = 0.0f;
    }
  }
  __syncthreads();
  const int n = n_s;
  if (n > 0) {
    const float t2 = thr_s;
    const int p0 = pfx[tid], p1 = pfx[tid + 1];
    const int base = tid * 256;
    for (int j = 0; j < 2; ++j) {
      const int r = ridx_s[j];
      if (r >= p0 && r < p1) {
        int need = r - p0;
        int sel = -1;
        for (int i = 0; i < 256; ++i) {
          if (s[base + i] < t2) {
            if (need == 0) { sel = base + i; break; }
            --need;
          }
        }
        coords[(size_t)b * 10 + 6 + j * 2 + 0] = (float)(sel & 255);
        coords[(size_t)b * 10 + 6 + j * 2 + 1] = (float)(sel >> 8);
      }
    }
  }
}

// ---------------------------------------------------------------------------
extern "C" void kernel_launch(void* const* d_in, const int* in_sizes, int n_in,
                              void* d_out, int out_size, void* d_ws, size_t ws_size,
                              hipStream_t stream) {
  (void)in_sizes; (void)n_in; (void)out_size; (void)ws_size;
  const float* x  = (const float*)d_in[0];
  const float* w1 = (const float*)d_in[1];
  const float* g1 = (const float*)d_in[2];
  const float* b1 = (const float*)d_in[3];
  const float* m1 = (const float*)d_in[4];
  const float* v1 = (const float*)d_in[5];
  const float* w2 = (const float*)d_in[6];
  const float* g2 = (const float*)d_in[7];
  const float* b2 = (const float*)d_in[8];
  const float* m2 = (const float*)d_in[9];
  const float* v2 = (const float*)d_in[10];
  const float* w3 = (const float*)d_in[11];
  const float* b3 = (const float*)d_in[12];

  float* out = (float*)d_out;
  float* heat = out;                         // [32,1,256,256]
  float* coords = out + (size_t)32 * 65536;  // [32,1,5,2]
  float* labels = coords + 320;              // [32,1,5]
  float* logits = labels + 160;              // [32,1,256,256]

  // Transposed weights live in the logits region (overwritten by upsample_k
  // only after both convs have consumed them — stream-ordered, no hazard).
  float* w1t = logits;            // 256*9*64 floats
  float* w2t = logits + 147456;   // 64*9*64 floats

  float* h1 = (float*)d_ws;                        // [32,64,64,64]
  float* h2 = h1 + (size_t)32 * 64 * 64 * 64;      // [32,64,64,64]
  float* lg64 = h1;                                // reuse after conv2
  float* cand = h1 + 131072;
  float* ncnt = h1 + 135168;
  float* pmax = h1 + 167936;

  transpose_w4<<<144, 256, 0, stream>>>(w1, w1t, 2304);
  transpose_w4<<<36, 256, 0, stream>>>(w2, w2t, 576);
  conv3x3_bn_relu<256><<<1024, 512, 0, stream>>>(x, w1t, g1, b1, m1, v1, h1);
  conv3x3_bn_relu<64><<<1024, 512, 0, stream>>>(h1, w2t, g2, b2, m2, v2, h2);
  logits64_k<<<512, 256, 0, stream>>>(h2, w3, b3, lg64);
  upsample_k<<<2048, 256, 0, stream>>>(lg64, logits, heat);
  pos_stripe<<<512, 256, 0, stream>>>(heat, cand);
  pos_final<<<32, 64, 0, stream>>>(cand, coords, labels);
  neg_count<<<128, 256, 0, stream>>>(heat, ncnt, pmax);
  neg_select<<<32, 256, 0, stream>>>(heat, ncnt, pmax, coords, labels);
}

// Round 6
// 782.439 us; speedup vs baseline: 7.2515x; 1.0618x over previous
//
#include <hip/hip_runtime.h>
#include <stdint.h>
#include <math.h>

#define NEG_INF (-__builtin_inff())
#define IDX_SENT 0x7fffffff

typedef __attribute__((address_space(1))) const void gas_t;   // global
typedef __attribute__((address_space(3))) void las_t;         // LDS

// ---------------------------------------------------------------------------
// JAX threefry2x32 (20 rounds), exact replication.
// ---------------------------------------------------------------------------
__device__ __forceinline__ void threefry2x32(uint32_t k0, uint32_t k1,
                                             uint32_t x0, uint32_t x1,
                                             uint32_t* o0, uint32_t* o1) {
  const uint32_t ks2 = k0 ^ k1 ^ 0x1BD11BDAu;
  uint32_t ks[3] = {k0, k1, ks2};
  const int rot[2][4] = {{13, 15, 26, 6}, {17, 29, 16, 24}};
  x0 += ks[0];
  x1 += ks[1];
#pragma unroll
  for (int i = 0; i < 5; ++i) {
#pragma unroll
    for (int j = 0; j < 4; ++j) {
      const int r = rot[i & 1][j];
      x0 += x1;
      x1 = (x1 << r) | (x1 >> (32 - r));
      x1 ^= x0;
    }
    x0 += ks[(i + 1) % 3];
    x1 += ks[(i + 2) % 3] + (uint32_t)(i + 1);
  }
  *o0 = x0;
  *o1 = x1;
}

__device__ __forceinline__ float bits_to_uniform(uint32_t bits) {
  return __uint_as_float((bits >> 9) | 0x3f800000u) - 1.0f;
}

// top3 ordered by (value desc, index asc) — matches jax.lax.top_k tie-break.
__device__ __forceinline__ void top3_insert(float v, int idx, float tv[3], int ti[3]) {
  if ((v > tv[2]) || (v == tv[2] && idx < ti[2])) {
    tv[2] = v; ti[2] = idx;
    if ((tv[2] > tv[1]) || (tv[2] == tv[1] && ti[2] < ti[1])) {
      float fv = tv[1]; int fi = ti[1];
      tv[1] = tv[2]; ti[1] = ti[2];
      tv[2] = fv;     ti[2] = fi;
      if ((tv[1] > tv[0]) || (tv[1] == tv[0] && ti[1] < ti[0])) {
        fv = tv[0]; fi = ti[0];
        tv[0] = tv[1]; ti[0] = ti[1];
        tv[1] = fv;    ti[1] = fi;
      }
    }
  }
}

// ---------------------------------------------------------------------------
// Weight transpose: w[oc][IC][3][3] -> wt[(ic*9+k)][64].
// ---------------------------------------------------------------------------
__global__ __launch_bounds__(256) void transpose_w4(
    const float* __restrict__ w, float* __restrict__ wt, int IC9) {
  const int idx = blockIdx.x * 256 + threadIdx.x;   // qrow*64 + oc
  const int qrow = idx >> 6;
  const int oc = idx & 63;
  const float4 v = *(const float4*)&w[(size_t)oc * IC9 + qrow * 4];
  wt[(size_t)(qrow * 4 + 0) * 64 + oc] = v.x;
  wt[(size_t)(qrow * 4 + 1) * 64 + oc] = v.y;
  wt[(size_t)(qrow * 4 + 2) * 64 + oc] = v.z;
  wt[(size_t)(qrow * 4 + 3) * 64 + oc] = v.w;
}

// ---------------------------------------------------------------------------
// conv3x3 (pad 1) + inference BN + ReLU.  x:[32,IC,64,64] wt:[(IC*9)][64]
// out:[32,64,64,64].
// Round-12 diagnosis: VALUBusy pinned at 66-71% across R0/R2/R5 (16
// waves/CU, varying intensity/staging) -> structural stall, not TLP.
// Root cause: s_load weights (SMEM) and ds_read pixels (DS) share lgkmcnt
// and complete mutually out-of-order -> every wait is a conservative
// lgkmcnt(0) draining the whole weight stream into each pixel-read dep;
// ~200cy exposed per (ic,ky) in EVERY wave (co-resident waves stall
// identically -> more TLP can't help).
// Fix: depth-1 software pipeline at (ic,ky)-unit granularity. At unit u's
// compute-top, issue ALL of unit u+1's loads (2 ds_read + 6 s_load_x4,
// 24 dwords; A/B double-buffered = 48 SGPR). The single lgkmcnt(0) then
// sits ~192 fma-cycles after issue -> latency covered; a full drain is
// exactly the wanted semantic. All indexing static (explicit A/B names,
// ic unrolled by 2 for parity) — no dynamic-index scratch (rule #20).
// Kept from R5: global_load_lds DMA staging (vmcnt — independent of
// lgkm; zero staging VALU), LDS zeroed once for halo, (512,3) spill
// guard (R3/R4: (512,N) acts as min-blocks/CU -> VGPR cap 2048/8N; N=3
// gives cap ~85, spill-proof). Wave shape = R2's proven 4px x 8oc.
// Grid: 32 b x 16 tiles (8 rows x 32 cols) = 512 blocks, 512 thr = 8 waves.
// Accumulation order per output element: (icb, ic, ky, kx) — identical to
// all previous rounds => bit-identical numerics.
// ---------------------------------------------------------------------------
template <int IC>
__global__ __launch_bounds__(512, 3) void conv3x3_bn_relu(
    const float* __restrict__ x, const float* __restrict__ wt,
    const float* __restrict__ g, const float* __restrict__ bb,
    const float* __restrict__ m, const float* __restrict__ vv,
    float* __restrict__ out) {
  __shared__ float xs[2][8][10][36];   // dbuf x 8 ic x 10 halo rows x 36 cols (34 used)

  const int tid = threadIdx.x;
  const int blk = blockIdx.x;
  const int b = blk >> 4;
  const int tile = blk & 15;
  const int by = (tile >> 1) << 3;   // 8-row tile
  const int bx = (tile & 1) << 5;    // 32-col tile
  const int wv = __builtin_amdgcn_readfirstlane(tid >> 6);  // wave id 0..7
  const int lane = tid & 63;
  const int r = lane & 7;            // output row in tile
  const int lc = (lane >> 3) << 2;   // 0,4,..,28 col base (4 px)
  const int ocbase = wv << 3;        // wave-uniform oc base (8 ocs)

  // staging decomposition: wave wv DMAs ic=wv, lanes 0..33 = halo cols
  const int sc = lane;
  const int gx = bx + sc - 1;
  const bool cok = (sc < 34) && (gx >= 0) && (gx < 64);

  float acc[4][8];
#pragma unroll
  for (int p = 0; p < 4; ++p)
#pragma unroll
    for (int o = 0; o < 8; ++o) acc[p][o] = 0.0f;

  // ---- zero LDS once: never-DMA'd halo cells must read as 0 ----
  for (int l = tid; l < 2 * 8 * 10 * 36; l += 512)
    (&xs[0][0][0][0])[l] = 0.0f;
  __syncthreads();

  // DMA one icb (8 ics, wave wv handles ic icb0+wv) into buffer `buf`.
  auto stage = [&](int buf, int icb0) {
    if (cok) {
      const float* gb = x + ((size_t)b * IC + icb0 + wv) * 4096 + (by - 1) * 64 + gx;
#pragma unroll
      for (int rr = 0; rr < 10; ++rr) {
        const int gy = by + rr - 1;
        if (gy >= 0 && gy < 64) {
          __builtin_amdgcn_global_load_lds(
              (gas_t*)(const void*)(gb + rr * 64),
              (las_t*)(void*)(&xs[buf][wv][rr][0]),
              4, 0, 0);
        }
      }
    }
  };

  // ---- prologue: DMA icb=0 into buffer 0 ----
  stage(0, 0);
  __syncthreads();

  int cur = 0;
  for (int icb = 0; icb < IC; icb += 8) {
    // next-icb DMA issued early (vmcnt; drains at the end-of-icb barrier)
    if (icb + 8 < IC) stage(cur ^ 1, icb + 8);

    const float* wbase = wt + (size_t)icb * 9 * 64 + ocbase;  // uniform

    float xvA[6], xvB[6];
    float4 wA[6], wB[6];

    // load unit (ic,ky): pixel row (ds_read b128+b64) + 6 weight float4
    // (uniform addr -> s_load). Issued a full unit ahead of use.
    auto loadu = [&](float* xv, float4* w, int ic, int ky) {
      *(float4*)&xv[0] = *(const float4*)&xs[cur][ic][r + ky][lc];
      *(float2*)&xv[4] = *(const float2*)&xs[cur][ic][r + ky][lc + 4];
      const float4* wp = (const float4*)(wbase + (ic * 9 + ky * 3) * 64);
      w[0] = wp[0];  w[1] = wp[1];      // kx=0, oc quads 0,1
      w[2] = wp[16]; w[3] = wp[17];     // kx=1
      w[4] = wp[32]; w[5] = wp[33];     // kx=2
    };
    // fma order (kx, q, p) — identical nesting to all previous rounds.
    auto compute = [&](const float* xv, const float4* w) {
#pragma unroll
      for (int kx = 0; kx < 3; ++kx)
#pragma unroll
        for (int q = 0; q < 2; ++q) {
          const float4 w4 = w[kx * 2 + q];
#pragma unroll
          for (int p = 0; p < 4; ++p) {
            acc[p][4 * q + 0] = fmaf(xv[kx + p], w4.x, acc[p][4 * q + 0]);
            acc[p][4 * q + 1] = fmaf(xv[kx + p], w4.y, acc[p][4 * q + 1]);
            acc[p][4 * q + 2] = fmaf(xv[kx + p], w4.z, acc[p][4 * q + 2]);
            acc[p][4 * q + 3] = fmaf(xv[kx + p], w4.w, acc[p][4 * q + 3]);
          }
        }
    };

    // 24 units, depth-1 pipelined; ic unrolled by 2 so A/B parity is static.
    loadu(xvA, wA, 0, 0);
    for (int ic2 = 0; ic2 < 4; ++ic2) {
      const int ic0 = ic2 * 2;
      loadu(xvB, wB, ic0, 1);       compute(xvA, wA);   // (ic0, 0)
      loadu(xvA, wA, ic0, 2);       compute(xvB, wB);   // (ic0, 1)
      loadu(xvB, wB, ic0 + 1, 0);   compute(xvA, wA);   // (ic0, 2)
      loadu(xvA, wA, ic0 + 1, 1);   compute(xvB, wB);   // (ic0+1, 0)
      loadu(xvB, wB, ic0 + 1, 2);   compute(xvA, wA);   // (ic0+1, 1)
      if (ic2 < 3) loadu(xvA, wA, ic0 + 2, 0);
      compute(xvB, wB);                                  // (ic0+1, 2)
    }

    __syncthreads();
    cur ^= 1;
  }

  // ---- epilogue: BN + ReLU + float4 store ----
#pragma unroll
  for (int o = 0; o < 8; ++o) {
    const int oc = ocbase + o;
    const float sc2 = g[oc] * (1.0f / sqrtf(vv[oc] + 1e-5f));
    const float sh = bb[oc] - m[oc] * sc2;
    float4 v;
    v.x = fmaxf(fmaf(acc[0][o], sc2, sh), 0.0f);
    v.y = fmaxf(fmaf(acc[1][o], sc2, sh), 0.0f);
    v.z = fmaxf(fmaf(acc[2][o], sc2, sh), 0.0f);
    v.w = fmaxf(fmaf(acc[3][o], sc2, sh), 0.0f);
    *(float4*)&out[(((size_t)b * 64 + oc) * 64 + (by + r)) * 64 + bx + lc] = v;
  }
}

// ---------------------------------------------------------------------------
// 1x1 conv (64->1) + bias into lg64[32][4096].  Grid 32*16 blocks.
// ---------------------------------------------------------------------------
__global__ __launch_bounds__(256) void logits64_k(
    const float* __restrict__ h2, const float* __restrict__ w3,
    const float* __restrict__ b3, float* __restrict__ lg64) {
  const int blk = blockIdx.x;
  const int b = blk >> 4;
  const int p = ((blk & 15) << 8) + threadIdx.x;
  __shared__ float wvv[64];
  if (threadIdx.x < 64) wvv[threadIdx.x] = w3[threadIdx.x];
  __syncthreads();
  float s = b3[0];
  const float* hp = h2 + (size_t)b * 64 * 4096 + p;
  for (int oc = 0; oc < 64; ++oc)
    s = fmaf(hp[(size_t)oc * 4096], wvv[oc], s);
  lg64[b * 4096 + p] = s;
}

// ---------------------------------------------------------------------------
// bilinear 64->256 (half-pixel, edge clamp) + sigmoid.
// ---------------------------------------------------------------------------
__global__ __launch_bounds__(256) void upsample_k(
    const float* __restrict__ lg64, float* __restrict__ logits,
    float* __restrict__ heat) {
  const int blk = blockIdx.x;
  const int b = blk >> 6;
  const int qq = ((blk & 63) << 10) + (threadIdx.x << 2);
  const float* lg = lg64 + b * 4096;
  const int oy = qq >> 8;
  const float sy = (float)oy * 0.25f - 0.375f;
  const float fy = floorf(sy);
  const int y0 = (int)fy;
  const float ty = sy - fy;
  const int y0c = y0 < 0 ? 0 : y0;
  const int y1c = (y0 + 1) > 63 ? 63 : (y0 + 1);
  const float* r0 = lg + y0c * 64;
  const float* r1 = lg + y1c * 64;
  float4 lo, he;
  float* lop = (float*)&lo;
  float* hep = (float*)&he;
#pragma unroll
  for (int j = 0; j < 4; ++j) {
    const int ox = (qq & 255) + j;
    const float sx = (float)ox * 0.25f - 0.375f;
    const float fx = floorf(sx);
    const int x0 = (int)fx;
    const float tx = sx - fx;
    const int x0c = x0 < 0 ? 0 : x0;
    const int x1c = (x0 + 1) > 63 ? 63 : (x0 + 1);
    const float v00 = r0[x0c], v01 = r0[x1c];
    const float v10 = r1[x0c], v11 = r1[x1c];
    const float vtop = v00 + (v01 - v00) * tx;
    const float vbot = v10 + (v11 - v10) * tx;
    const float val = vtop + (vbot - vtop) * ty;
    lop[j] = val;
    hep[j] = 1.0f / (1.0f + expf(-val));
  }
  const size_t o = (size_t)b * 65536 + qq;
  *(float4*)(logits + o) = lo;
  *(float4*)(heat + o) = he;
}

// ---------------------------------------------------------------------------
// Positive points, phase 1: per-stripe 9x9 NMS peak top3 + stripe argmax.
// ---------------------------------------------------------------------------
__global__ __launch_bounds__(256) void pos_stripe(
    const float* __restrict__ heat, float* __restrict__ cand) {
  const int b = blockIdx.x >> 4;
  const int stripe = blockIdx.x & 15;
  const int y0 = stripe << 4;
  const float* s = heat + (size_t)b * 65536;
  const int tid = threadIdx.x;
  __shared__ float sm[24][256];
  __shared__ float rm[24][256];
  __shared__ float rv[256 * 3];
  __shared__ int ri[256 * 3];
  __shared__ float mvv[256];
  __shared__ int mii[256];
  __shared__ float rv2[24];
  __shared__ int ri2[24];
  __shared__ float mv2[8];
  __shared__ int mi2[8];

  for (int l = tid; l < 24 * 256; l += 256) {
    const int rr = l >> 8, xx = l & 255;
    const int gy = y0 - 4 + rr;
    sm[rr][xx] = (gy >= 0 && gy < 256) ? s[gy * 256 + xx] : NEG_INF;
  }
  __syncthreads();
  for (int l = tid; l < 24 * 256; l += 256) {
    const int rr = l >> 8, xx = l & 255;
    const int lo = (xx - 4 < 0) ? 0 : xx - 4;
    const int hi = (xx + 4 > 255) ? 255 : xx + 4;
    float mx = NEG_INF;
    for (int x2 = lo; x2 <= hi; ++x2) mx = fmaxf(mx, sm[rr][x2]);
    rm[rr][xx] = mx;
  }
  __syncthreads();

  float tv[3] = {NEG_INF, NEG_INF, NEG_INF};
  int ti[3] = {IDX_SENT, IDX_SENT, IDX_SENT};
  float bmax = NEG_INF;
  int bidx = IDX_SENT;
  for (int l = tid; l < 16 * 256; l += 256) {
    const int ry = l >> 8, xx = l & 255;
    const int lr = ry + 4;
    const float v = sm[lr][xx];
    float lm = rm[lr - 4][xx];
#pragma unroll
    for (int d = -3; d <= 4; ++d) lm = fmaxf(lm, rm[lr + d][xx]);
    const int gidx = (y0 + ry) * 256 + xx;
    if (v > bmax) { bmax = v; bidx = gidx; }
    if (v == lm && v > 0.1f) top3_insert(v, gidx, tv, ti);
  }

  rv[tid * 3 + 0] = tv[0]; rv[tid * 3 + 1] = tv[1]; rv[tid * 3 + 2] = tv[2];
  ri[tid * 3 + 0] = ti[0]; ri[tid * 3 + 1] = ti[1]; ri[tid * 3 + 2] = ti[2];
  mvv[tid] = bmax; mii[tid] = bidx;
  __syncthreads();

  if (tid < 8) {
    float av[3] = {NEG_INF, NEG_INF, NEG_INF};
    int ai[3] = {IDX_SENT, IDX_SENT, IDX_SENT};
    float am = NEG_INF; int amI = IDX_SENT;
    for (int t = tid * 32; t < tid * 32 + 32; ++t) {
      for (int k = 0; k < 3; ++k) top3_insert(rv[t * 3 + k], ri[t * 3 + k], av, ai);
      if (mvv[t] > am || (mvv[t] == am && mii[t] < amI)) { am = mvv[t]; amI = mii[t]; }
    }
    rv2[tid * 3 + 0] = av[0]; rv2[tid * 3 + 1] = av[1]; rv2[tid * 3 + 2] = av[2];
    ri2[tid * 3 + 0] = ai[0]; ri2[tid * 3 + 1] = ai[1]; ri2[tid * 3 + 2] = ai[2];
    mv2[tid] = am; mi2[tid] = amI;
  }
  __syncthreads();

  if (tid == 0) {
    float fv[3] = {NEG_INF, NEG_INF, NEG_INF};
    int fi[3] = {IDX_SENT, IDX_SENT, IDX_SENT};
    for (int t = 0; t < 24; ++t) top3_insert(rv2[t], ri2[t], fv, fi);
    float gbv = NEG_INF; int gbi = IDX_SENT;
    for (int t = 0; t < 8; ++t)
      if (mv2[t] > gbv || (mv2[t] == gbv && mi2[t] < gbi)) { gbv = mv2[t]; gbi = mi2[t]; }
    float* c = cand + ((size_t)b * 16 + stripe) * 8;
    c[0] = fv[0]; c[1] = __int_as_float(fi[0]);
    c[2] = fv[1]; c[3] = __int_as_float(fi[1]);
    c[4] = fv[2]; c[5] = __int_as_float(fi[2]);
    c[6] = gbv;   c[7] = __int_as_float(gbi);
  }
}

// ---------------------------------------------------------------------------
// Positive points, phase 2: reduce 16 stripe candidates -> final outputs.
// ---------------------------------------------------------------------------
__global__ void pos_final(const float* __restrict__ cand,
                          float* __restrict__ coords, float* __restrict__ labels) {
  const int b = blockIdx.x;
  if (threadIdx.x != 0) return;
  float fv[3] = {NEG_INF, NEG_INF, NEG_INF};
  int fi[3] = {IDX_SENT, IDX_SENT, IDX_SENT};
  float gbv = NEG_INF; int gbi = IDX_SENT;
  for (int st = 0; st < 16; ++st) {
    const float* c = cand + ((size_t)b * 16 + st) * 8;
    for (int k = 0; k < 3; ++k)
      top3_insert(c[2 * k], __float_as_int(c[2 * k + 1]), fv, fi);
    const float mv = c[6]; const int mi = __float_as_int(c[7]);
    if (mv > gbv || (mv == gbv && mi < gbi)) { gbv = mv; gbi = mi; }
  }
  float* co = coords + (size_t)b * 10;
  float* la = labels + (size_t)b * 5;
  const bool any_peak = (fi[0] != IDX_SENT);
  const int i0 = any_peak ? fi[0] : gbi;
  co[0] = (float)(i0 & 255);
  co[1] = (float)(i0 >> 8);
  la[0] = 1.0f;
  for (int k = 1; k < 3; ++k) {
    const bool valid = (fi[k] != IDX_SENT);
    co[k * 2 + 0] = valid ? (float)(fi[k] & 255) : 0.0f;
    co[k * 2 + 1] = valid ? (float)(fi[k] >> 8) : 0.0f;
    la[k] = valid ? 1.0f : -1.0f;
  }
}

// ---------------------------------------------------------------------------
// Negative points, phase 1: per-64px-chunk count of (heat<0.3) + partial max.
// ---------------------------------------------------------------------------
__global__ __launch_bounds__(256) void neg_count(
    const float* __restrict__ heat, float* __restrict__ ncnt,
    float* __restrict__ pmax) {
  const int blk = blockIdx.x;
  const int b = blk >> 2;
  const int part = blk & 3;
  const int tid = threadIdx.x;
  const int chunk = (part << 8) + tid;
  const float4* s = (const float4*)(heat + (size_t)b * 65536 + chunk * 64);
  int c = 0;
  float mx = NEG_INF;
  for (int i = 0; i < 16; ++i) {
    const float4 v = s[i];
    c += (v.x < 0.3f) + (v.y < 0.3f) + (v.z < 0.3f) + (v.w < 0.3f);
    mx = fmaxf(mx, fmaxf(fmaxf(v.x, v.y), fmaxf(v.z, v.w)));
  }
  ncnt[b * 1024 + chunk] = (float)c;
  __shared__ float mxs[256];
  mxs[tid] = mx;
  __syncthreads();
  if (tid == 0) {
    float gmx = NEG_INF;
    for (int t = 0; t < 256; ++t) gmx = fmaxf(gmx, mxs[t]);
    pmax[blk] = gmx;
  }
}

// ---------------------------------------------------------------------------
// Negative points, phase 2: prefix, PRNG rank select, rescan.
// ---------------------------------------------------------------------------
__global__ __launch_bounds__(256) void neg_select(
    const float* __restrict__ heat, const float* __restrict__ ncnt,
    const float* __restrict__ pmax, float* __restrict__ coords,
    float* __restrict__ labels) {
  const int b = blockIdx.x;
  const int tid = threadIdx.x;
  const float* s = heat + (size_t)b * 65536;
  __shared__ float cnt[1024];
  __shared__ float c256[256];
  __shared__ int pfx[257];
  __shared__ float thr_s;
  __shared__ int fb_s;
  __shared__ int n_s;
  __shared__ int ridx_s[2];

  for (int l = tid; l < 1024; l += 256) cnt[l] = ncnt[b * 1024 + l];
  __syncthreads();
  c256[tid] = cnt[4 * tid] + cnt[4 * tid + 1] + cnt[4 * tid + 2] + cnt[4 * tid + 3];
  __syncthreads();
  if (tid == 0) {
    int tot = 0;
    for (int t = 0; t < 256; ++t) tot += (int)c256[t];
    const float gm = fmaxf(fmaxf(pmax[b * 4], pmax[b * 4 + 1]),
                           fmaxf(pmax[b * 4 + 2], pmax[b * 4 + 3]));
    fb_s = (tot > 0) ? 0 : 1;
    thr_s = (tot > 0) ? 0.3f : gm;
  }
  __syncthreads();
  if (fb_s) {
    const float t2 = thr_s;
    const int base = tid * 256;
    int c = 0;
    for (int i = 0; i < 256; ++i) c += (s[base + i] < t2) ? 1 : 0;
    c256[tid] = (float)c;
    __syncthreads();
  }
  if (tid == 0) {
    int run = 0;
    for (int t = 0; t < 256; ++t) { pfx[t] = run; run += (int)c256[t]; }
    pfx[256] = run;
    const int n = run;
    n_s = n;
    uint32_t k0, k1, a0, a1;
    threefry2x32(0u, 42u, 0u, (uint32_t)b, &k0, &k1);
    threefry2x32(k0, k1, 0u, 0u, &a0, &a1);
    const uint32_t bits0 = a0 ^ a1;
    threefry2x32(k0, k1, 0u, 1u, &a0, &a1);
    const uint32_t bits1 = a0 ^ a1;
    const float u0 = bits_to_uniform(bits0);
    const float u1 = bits_to_uniform(bits1);
    const float nf = (float)(n > 1 ? n : 1);
    int r0 = (int)(u0 * nf);
    int r1 = (int)(u1 * nf);
    const int rmax = (n - 1 > 0) ? n - 1 : 0;
    ridx_s[0] = r0 < rmax ? r0 : rmax;
    ridx_s[1] = r1 < rmax ? r1 : rmax;
    labels[(size_t)b * 5 + 3] = 0.0f;
    labels[(size_t)b * 5 + 4] = 0.0f;
    if (n == 0) {
      coords[(size_t)b * 10 + 6] = 0.0f; coords[(size_t)b * 10 + 7] = 0.0f;
      coords[(size_t)b * 10 + 8] = 0.0f; coords[(size_t)b * 10 + 9] = 0.0f;
    }
  }
  __syncthreads();
  const int n = n_s;
  if (n > 0) {
    const float t2 = thr_s;
    const int p0 = pfx[tid], p1 = pfx[tid + 1];
    const int base = tid * 256;
    for (int j = 0; j < 2; ++j) {
      const int r = ridx_s[j];
      if (r >= p0 && r < p1) {
        int need = r - p0;
        int sel = -1;
        for (int i = 0; i < 256; ++i) {
          if (s[base + i] < t2) {
            if (need == 0) { sel = base + i; break; }
            --need;
          }
        }
        coords[(size_t)b * 10 + 6 + j * 2 + 0] = (float)(sel & 255);
        coords[(size_t)b * 10 + 6 + j * 2 + 1] = (float)(sel >> 8);
      }
    }
  }
}

// ---------------------------------------------------------------------------
extern "C" void kernel_launch(void* const* d_in, const int* in_sizes, int n_in,
                              void* d_out, int out_size, void* d_ws, size_t ws_size,
                              hipStream_t stream) {
  (void)in_sizes; (void)n_in; (void)out_size; (void)ws_size;
  const float* x  = (const float*)d_in[0];
  const float* w1 = (const float*)d_in[1];
  const float* g1 = (const float*)d_in[2];
  const float* b1 = (const float*)d_in[3];
  const float* m1 = (const float*)d_in[4];
  const float* v1 = (const float*)d_in[5];
  const float* w2 = (const float*)d_in[6];
  const float* g2 = (const float*)d_in[7];
  const float* b2 = (const float*)d_in[8];
  const float* m2 = (const float*)d_in[9];
  const float* v2 = (const float*)d_in[10];
  const float* w3 = (const float*)d_in[11];
  const float* b3 = (const float*)d_in[12];

  float* out = (float*)d_out;
  float* heat = out;                         // [32,1,256,256]
  float* coords = out + (size_t)32 * 65536;  // [32,1,5,2]
  float* labels = coords + 320;              // [32,1,5]
  float* logits = labels + 160;              // [32,1,256,256]

  // Transposed weights live in the logits region (overwritten by upsample_k
  // only after both convs have consumed them — stream-ordered, no hazard).
  float* w1t = logits;            // 256*9*64 floats
  float* w2t = logits + 147456;   // 64*9*64 floats

  float* h1 = (float*)d_ws;                        // [32,64,64,64]
  float* h2 = h1 + (size_t)32 * 64 * 64 * 64;      // [32,64,64,64]
  float* lg64 = h1;                                // reuse after conv2
  float* cand = h1 + 131072;
  float* ncnt = h1 + 135168;
  float* pmax = h1 + 167936;

  transpose_w4<<<144, 256, 0, stream>>>(w1, w1t, 2304);
  transpose_w4<<<36, 256, 0, stream>>>(w2, w2t, 576);
  conv3x3_bn_relu<256><<<512, 512, 0, stream>>>(x, w1t, g1, b1, m1, v1, h1);
  conv3x3_bn_relu<64><<<512, 512, 0, stream>>>(h1, w2t, g2, b2, m2, v2, h2);
  logits64_k<<<512, 256, 0, stream>>>(h2, w3, b3, lg64);
  upsample_k<<<2048, 256, 0, stream>>>(lg64, logits, heat);
  pos_stripe<<<512, 256, 0, stream>>>(heat, cand);
  pos_final<<<32, 64, 0, stream>>>(cand, coords, labels);
  neg_count<<<128, 256, 0, stream>>>(heat, ncnt, pmax);
  neg_select<<<32, 256, 0, stream>>>(heat, ncnt, pmax, coords, labels);
}